// Round 1
// baseline (297.629 us; speedup 1.0000x reference)
//
#include <hip/hip_runtime.h>

typedef __bf16 bf16;
typedef __bf16 bf16x8 __attribute__((ext_vector_type(8)));
typedef __bf16 bf16x4 __attribute__((ext_vector_type(4)));
typedef float f32x4 __attribute__((ext_vector_type(4)));

// Problem constants
#define BB 4
#define TT 2048
#define CC 1024
#define HH 16
#define DD 64
#define MM (BB*TT)   // 8192

// ---------------- convert f32 -> bf16 ----------------
__global__ void conv_f32_bf16(const float* __restrict__ in, bf16* __restrict__ out, int n) {
    int i = (blockIdx.x * blockDim.x + threadIdx.x) * 4;
    int stride = gridDim.x * blockDim.x * 4;
    for (; i < n; i += stride) {
        float4 v = *(const float4*)(in + i);
        bf16x4 o;
        o[0] = (bf16)v.x; o[1] = (bf16)v.y; o[2] = (bf16)v.z; o[3] = (bf16)v.w;
        *(bf16x4*)(out + i) = o;
    }
}

// ---------------- transpose + convert: in [K][N] f32 -> out [N][K] bf16 ----------------
__global__ void transpose_f32_bf16(const float* __restrict__ in, bf16* __restrict__ out,
                                   int K, int N) {
    __shared__ bf16 tile[64][65];
    int n0 = blockIdx.x * 64, k0 = blockIdx.y * 64;
    int tc = threadIdx.x & 63, tr = threadIdx.x >> 6;  // 4 rows per pass
    #pragma unroll
    for (int p = 0; p < 16; ++p) {
        int k = tr + p * 4;
        tile[k][tc] = (bf16)in[(size_t)(k0 + k) * N + n0 + tc];
    }
    __syncthreads();
    #pragma unroll
    for (int p = 0; p < 16; ++p) {
        int n = tr + p * 4;
        out[(size_t)(n0 + n) * K + k0 + tc] = tile[tc][n];
    }
}

// ---------------- GEMM: C[M][N] = A[M][K] @ Bt[N][K]^T + bias ----------------
// MODE 0: scatter to q,k,v bf16 buffers in [B,H,T,D] layout
// MODE 1: write f32 out [M][N]
template<int MODE>
__global__ __launch_bounds__(256) void gemm_bt(
    const bf16* __restrict__ A, const bf16* __restrict__ Bt,
    const float* __restrict__ bias,
    void* __restrict__ out0, void* __restrict__ out1, void* __restrict__ out2,
    int M, int N, int K)
{
    constexpr int BM = 128, BN = 128, BK = 64, PK = BK + 8;  // pitch 72 elem = 144B, 16B-aligned
    __shared__ bf16 As[BM * PK];
    __shared__ bf16 Bs[BN * PK];

    int bx = blockIdx.x, by = blockIdx.y;
    int tid = threadIdx.x;
    int lane = tid & 63, wave = tid >> 6;
    int wr = wave >> 1, wc = wave & 1;
    int l15 = lane & 15, l4 = lane >> 4;

    const bf16* Ab = A + (size_t)(by * BM) * K;
    const bf16* Bb = Bt + (size_t)(bx * BN) * K;

    f32x4 acc[4][4] = {};

    int srow = tid >> 3;         // 0..31
    int scol = (tid & 7) * 8;    // 0..56

    for (int k0 = 0; k0 < K; k0 += BK) {
        __syncthreads();
        #pragma unroll
        for (int p = 0; p < 4; ++p) {
            int r = srow + p * 32;
            bf16x8 va = *(const bf16x8*)(Ab + (size_t)r * K + k0 + scol);
            *(bf16x8*)(&As[r * PK + scol]) = va;
            bf16x8 vb = *(const bf16x8*)(Bb + (size_t)r * K + k0 + scol);
            *(bf16x8*)(&Bs[r * PK + scol]) = vb;
        }
        __syncthreads();
        #pragma unroll
        for (int kk = 0; kk < 2; ++kk) {
            bf16x8 af[4], bf_[4];
            #pragma unroll
            for (int m = 0; m < 4; ++m)
                af[m] = *(const bf16x8*)(&As[(wr * 64 + m * 16 + l15) * PK + kk * 32 + l4 * 8]);
            #pragma unroll
            for (int n = 0; n < 4; ++n)
                bf_[n] = *(const bf16x8*)(&Bs[(wc * 64 + n * 16 + l15) * PK + kk * 32 + l4 * 8]);
            #pragma unroll
            for (int m = 0; m < 4; ++m)
                #pragma unroll
                for (int n = 0; n < 4; ++n)
                    acc[m][n] = __builtin_amdgcn_mfma_f32_16x16x32_bf16(af[m], bf_[n], acc[m][n], 0, 0, 0);
        }
    }

    #pragma unroll
    for (int m = 0; m < 4; ++m) {
        #pragma unroll
        for (int n = 0; n < 4; ++n) {
            int row0 = by * BM + wr * 64 + m * 16 + l4 * 4;
            int col  = bx * BN + wc * 64 + n * 16 + l15;
            float bv = bias[col];
            #pragma unroll
            for (int i = 0; i < 4; ++i) {
                int row = row0 + i;
                float v = acc[m][n][i] + bv;
                if constexpr (MODE == 0) {
                    int which = col >> 10;   // 0=q 1=k 2=v
                    int c = col & 1023;
                    int h = c >> 6, d = c & 63;
                    int b = row >> 11, t = row & 2047;
                    bf16* dst = (bf16*)(which == 0 ? out0 : which == 1 ? out1 : out2);
                    dst[(((size_t)(b * HH + h)) * TT + t) * DD + d] = (bf16)v;
                } else {
                    ((float*)out0)[(size_t)row * N + col] = v;
                }
            }
        }
    }
}

// ---------------- causal flash attention ----------------
// Q,K,V: bf16 [B*H][T][D].  Y: bf16 [B][T][C] with c = h*64+d.
__global__ __launch_bounds__(256) void attn_kernel(
    const bf16* __restrict__ Q, const bf16* __restrict__ Kb, const bf16* __restrict__ Vb,
    bf16* __restrict__ Y)
{
    constexpr int PD = DD + 8;   // 72 elem pitch (144B, 16B aligned)
    constexpr int PS = 68;       // f32 pitch
    __shared__ bf16 Qs[64 * PD];
    __shared__ bf16 Ks[64 * PD];
    __shared__ bf16 Vt[64 * PD];   // transposed: Vt[d][key]
    __shared__ bf16 Ps[64 * PD];
    __shared__ float Ss[64 * PS];
    __shared__ float m_s[64], l_s[64], sc_s[64];

    int bh = blockIdx.x;   // 0..63
    int qt = blockIdx.y;   // 0..31
    int b = bh >> 4, h = bh & 15;
    const bf16* Qg = Q + ((size_t)bh * TT + qt * 64) * DD;
    const bf16* Kg = Kb + (size_t)bh * TT * DD;
    const bf16* Vg = Vb + (size_t)bh * TT * DD;

    int tid = threadIdx.x;
    int lane = tid & 63, wave = tid >> 6;
    int l15 = lane & 15, l4 = lane >> 4;

    // stage Q (64 rows x 64 cols)
    {
        int r = tid >> 3, c = (tid & 7) * 8;
        #pragma unroll
        for (int p = 0; p < 2; ++p) {
            int rr = r + p * 32;
            bf16x8 v = *(const bf16x8*)(Qg + rr * DD + c);
            *(bf16x8*)(&Qs[rr * PD + c]) = v;
        }
    }
    if (tid < 64) { m_s[tid] = -3e38f; l_s[tid] = 0.f; }

    f32x4 o[4] = {};
    int qrow_lo = qt * 64;

    for (int kt = 0; kt <= qt; ++kt) {
        __syncthreads();
        // stage K rows + V transposed
        {
            int r = tid >> 3, c = (tid & 7) * 8;
            #pragma unroll
            for (int p = 0; p < 2; ++p) {
                int rr = r + p * 32;
                bf16x8 v = *(const bf16x8*)(Kg + ((size_t)kt * 64 + rr) * DD + c);
                *(bf16x8*)(&Ks[rr * PD + c]) = v;
                bf16x8 w = *(const bf16x8*)(Vg + ((size_t)kt * 64 + rr) * DD + c);
                #pragma unroll
                for (int i = 0; i < 8; ++i) Vt[(c + i) * PD + rr] = w[i];
            }
        }
        __syncthreads();

        // S = Q @ K^T  (wave handles 16 q-rows)
        f32x4 s[4] = {};
        #pragma unroll
        for (int kk = 0; kk < 2; ++kk) {
            bf16x8 qf = *(const bf16x8*)(&Qs[(wave * 16 + l15) * PD + kk * 32 + l4 * 8]);
            #pragma unroll
            for (int n = 0; n < 4; ++n) {
                bf16x8 kf = *(const bf16x8*)(&Ks[(n * 16 + l15) * PD + kk * 32 + l4 * 8]);
                s[n] = __builtin_amdgcn_mfma_f32_16x16x32_bf16(qf, kf, s[n], 0, 0, 0);
            }
        }
        // scale + causal mask, write S
        {
            int qb = wave * 16 + l4 * 4;
            #pragma unroll
            for (int n = 0; n < 4; ++n) {
                int key_g = kt * 64 + n * 16 + l15;
                #pragma unroll
                for (int i = 0; i < 4; ++i) {
                    int q_g = qrow_lo + qb + i;
                    float v = s[n][i] * 0.125f;
                    if (key_g > q_g) v = -1e30f;
                    Ss[(qb + i) * PS + n * 16 + l15] = v;
                }
            }
        }
        __syncthreads();

        // online softmax: 4 threads per row
        {
            int row = tid >> 2, sub = tid & 3;
            float vals[16];
            float mx = -3e38f;
            #pragma unroll
            for (int j = 0; j < 16; ++j) {
                vals[j] = Ss[row * PS + sub * 16 + j];
                mx = fmaxf(mx, vals[j]);
            }
            mx = fmaxf(mx, __shfl_xor(mx, 1));
            mx = fmaxf(mx, __shfl_xor(mx, 2));
            float m_old = m_s[row];
            float m_new = fmaxf(m_old, mx);
            float sum = 0.f;
            #pragma unroll
            for (int j = 0; j < 16; ++j) {
                float p = __expf(vals[j] - m_new);
                sum += p;
                Ps[row * PD + sub * 16 + j] = (bf16)p;
            }
            sum += __shfl_xor(sum, 1);
            sum += __shfl_xor(sum, 2);
            float scale = __expf(m_old - m_new);
            if (sub == 0) {
                m_s[row] = m_new;
                l_s[row] = l_s[row] * scale + sum;
                sc_s[row] = scale;
            }
        }
        __syncthreads();

        // rescale O, then O += P @ V
        {
            int qb = wave * 16 + l4 * 4;
            float scl[4];
            #pragma unroll
            for (int i = 0; i < 4; ++i) scl[i] = sc_s[qb + i];
            #pragma unroll
            for (int n = 0; n < 4; ++n)
                #pragma unroll
                for (int i = 0; i < 4; ++i) o[n][i] *= scl[i];
            #pragma unroll
            for (int kk = 0; kk < 2; ++kk) {
                bf16x8 pf = *(const bf16x8*)(&Ps[(wave * 16 + l15) * PD + kk * 32 + l4 * 8]);
                #pragma unroll
                for (int n = 0; n < 4; ++n) {
                    bf16x8 vf = *(const bf16x8*)(&Vt[(n * 16 + l15) * PD + kk * 32 + l4 * 8]);
                    o[n] = __builtin_amdgcn_mfma_f32_16x16x32_bf16(pf, vf, o[n], 0, 0, 0);
                }
            }
        }
    }

    // output: Y[b][t][h*64+d]
    {
        int qb = wave * 16 + l4 * 4;
        #pragma unroll
        for (int i = 0; i < 4; ++i) {
            float inv = 1.f / l_s[qb + i];
            int t = qrow_lo + qb + i;
            #pragma unroll
            for (int n = 0; n < 4; ++n) {
                int d = n * 16 + l15;
                Y[((size_t)(b * TT + t)) * CC + h * DD + d] = (bf16)(o[n][i] * inv);
            }
        }
    }
}

extern "C" void kernel_launch(void* const* d_in, const int* in_sizes, int n_in,
                              void* d_out, int out_size, void* d_ws, size_t ws_size,
                              hipStream_t stream) {
    const float* x      = (const float*)d_in[0];
    const float* w_attn = (const float*)d_in[1];
    const float* b_attn = (const float*)d_in[2];
    const float* w_proj = (const float*)d_in[3];
    const float* b_proj = (const float*)d_in[4];
    float* out = (float*)d_out;

    bf16* xb  = (bf16*)d_ws;                        // [8192][1024]
    bf16* waT = xb  + (size_t)MM * CC;              // [3072][1024]
    bf16* wpT = waT + (size_t)3 * CC * CC;          // [1024][1024]
    bf16* qb  = wpT + (size_t)CC * CC;              // [B*H][T][D]
    bf16* kb  = qb  + (size_t)MM * CC;
    bf16* vb  = kb  + (size_t)MM * CC;
    bf16* yb  = vb  + (size_t)MM * CC;              // [8192][1024]

    conv_f32_bf16<<<2048, 256, 0, stream>>>(x, xb, MM * CC);
    transpose_f32_bf16<<<dim3(3 * CC / 64, CC / 64), 256, 0, stream>>>(w_attn, waT, CC, 3 * CC);
    transpose_f32_bf16<<<dim3(CC / 64, CC / 64), 256, 0, stream>>>(w_proj, wpT, CC, CC);

    gemm_bt<0><<<dim3(3 * CC / 128, MM / 128), 256, 0, stream>>>(
        xb, waT, b_attn, qb, kb, vb, MM, 3 * CC, CC);

    attn_kernel<<<dim3(BB * HH, TT / 64), 256, 0, stream>>>(qb, kb, vb, yb);

    gemm_bt<1><<<dim3(CC / 128, MM / 128), 256, 0, stream>>>(
        yb, wpT, b_proj, out, nullptr, nullptr, MM, CC, CC);
}

// Round 2
// 271.928 us; speedup vs baseline: 1.0945x; 1.0945x over previous
//
#include <hip/hip_runtime.h>

typedef __bf16 bf16;
typedef __bf16 bf16x8 __attribute__((ext_vector_type(8)));
typedef __bf16 bf16x4 __attribute__((ext_vector_type(4)));
typedef float f32x4 __attribute__((ext_vector_type(4)));

// Problem constants
#define BB 4
#define TT 2048
#define CC 1024
#define HH 16
#define DD 64
#define MM (BB*TT)   // 8192

// softmax scale folded into q: 1/sqrt(64) * log2(e)  (we use exp2 in the kernel)
#define QSCALE (0.125f * 1.4426950408889634f)

__device__ __forceinline__ void async_copy16(const bf16* g, bf16* l) {
    __builtin_amdgcn_global_load_lds((const __attribute__((address_space(1))) void*)g,
                                     (__attribute__((address_space(3))) void*)l, 16, 0, 0);
}

// ---------------- convert f32 -> bf16 ----------------
__global__ void conv_f32_bf16(const float* __restrict__ in, bf16* __restrict__ out, int n) {
    int i = (blockIdx.x * blockDim.x + threadIdx.x) * 4;
    int stride = gridDim.x * blockDim.x * 4;
    for (; i < n; i += stride) {
        float4 v = *(const float4*)(in + i);
        bf16x4 o;
        o[0] = (bf16)v.x; o[1] = (bf16)v.y; o[2] = (bf16)v.z; o[3] = (bf16)v.w;
        *(bf16x4*)(out + i) = o;
    }
}

// ---------------- transpose + convert: in [K][N] f32 -> out [N][K] bf16 ----------------
__global__ void transpose_f32_bf16(const float* __restrict__ in, bf16* __restrict__ out,
                                   int K, int N) {
    __shared__ bf16 tile[64][65];
    int n0 = blockIdx.x * 64, k0 = blockIdx.y * 64;
    int tc = threadIdx.x & 63, tr = threadIdx.x >> 6;
    #pragma unroll
    for (int p = 0; p < 16; ++p) {
        int k = tr + p * 4;
        tile[k][tc] = (bf16)in[(size_t)(k0 + k) * N + n0 + tc];
    }
    __syncthreads();
    #pragma unroll
    for (int p = 0; p < 16; ++p) {
        int n = tr + p * 4;
        out[(size_t)(n0 + n) * K + k0 + tc] = tile[tc][n];
    }
}

// ---------------- bf16 transpose: [bh][t][d] -> [bh][d][t] ----------------
__global__ void transpose_v(const bf16* __restrict__ in, bf16* __restrict__ out) {
    __shared__ bf16 tile[64][72];
    int bh = blockIdx.x;
    int t0 = blockIdx.y * 64;
    int r = threadIdx.x >> 3, c = (threadIdx.x & 7) * 8;
    const bf16* src = in + ((size_t)bh * TT + t0) * DD;
    #pragma unroll
    for (int p = 0; p < 2; ++p) {
        int rr = r + p * 32;
        *(bf16x8*)(&tile[rr][c]) = *(const bf16x8*)(src + rr * DD + c);
    }
    __syncthreads();
    bf16* dst = out + (size_t)bh * DD * TT + t0;
    #pragma unroll
    for (int p = 0; p < 2; ++p) {
        int d = r + p * 32;
        bf16x8 v;
        #pragma unroll
        for (int j = 0; j < 8; ++j) v[j] = tile[c + j][d];
        *(bf16x8*)(dst + (size_t)d * TT + c) = v;
    }
}

// ---------------- GEMM: C[M][N] = A[M][K] @ Bt[N][K]^T + bias ----------------
// m97 structure: global_load_lds width-16 staging into linear LDS tiles.
// MODE 0: scatter to q,k,v bf16 buffers ([B,H,T,D]); q pre-scaled by QSCALE
// MODE 1: write f32 out [M][N]
template<int MODE>
__global__ __launch_bounds__(256) void gemm_bt(
    const bf16* __restrict__ A, const bf16* __restrict__ Bt,
    const float* __restrict__ bias,
    void* __restrict__ out0, void* __restrict__ out1, void* __restrict__ out2,
    int M, int N, int K)
{
    constexpr int BM = 128, BN = 128, BK = 64;
    __shared__ bf16 As[BM * BK];
    __shared__ bf16 Bs[BN * BK];

    int bx = blockIdx.x, by = blockIdx.y;
    int tid = threadIdx.x;
    int lane = tid & 63, wave = tid >> 6;
    int wr = wave >> 1, wc = wave & 1;
    int l15 = lane & 15, l4 = lane >> 4;

    const bf16* Ab = A + (size_t)(by * BM) * K;
    const bf16* Bb = Bt + (size_t)(bx * BN) * K;

    f32x4 acc[4][4] = {};

    int lrow = lane >> 3;         // 0..7
    int lcol = (lane & 7) * 8;    // 0..56

    for (int k0 = 0; k0 < K; k0 += BK) {
        __syncthreads();
        #pragma unroll
        for (int j = 0; j < 4; ++j) {
            int rbase = j * 32 + wave * 8;
            int r = rbase + lrow;
            async_copy16(Ab + (size_t)r * K + k0 + lcol, &As[rbase * BK]);
            async_copy16(Bb + (size_t)r * K + k0 + lcol, &Bs[rbase * BK]);
        }
        asm volatile("s_waitcnt vmcnt(0)" ::: "memory");
        __syncthreads();
        #pragma unroll
        for (int kk = 0; kk < 2; ++kk) {
            bf16x8 af[4], bf_[4];
            #pragma unroll
            for (int m = 0; m < 4; ++m)
                af[m] = *(const bf16x8*)(&As[(wr * 64 + m * 16 + l15) * BK + kk * 32 + l4 * 8]);
            #pragma unroll
            for (int n = 0; n < 4; ++n)
                bf_[n] = *(const bf16x8*)(&Bs[(wc * 64 + n * 16 + l15) * BK + kk * 32 + l4 * 8]);
            #pragma unroll
            for (int m = 0; m < 4; ++m)
                #pragma unroll
                for (int n = 0; n < 4; ++n)
                    acc[m][n] = __builtin_amdgcn_mfma_f32_16x16x32_bf16(af[m], bf_[n], acc[m][n], 0, 0, 0);
        }
    }

    #pragma unroll
    for (int m = 0; m < 4; ++m) {
        #pragma unroll
        for (int n = 0; n < 4; ++n) {
            int row0 = by * BM + wr * 64 + m * 16 + l4 * 4;
            int col  = bx * BN + wc * 64 + n * 16 + l15;
            float bv = bias[col];
            #pragma unroll
            for (int i = 0; i < 4; ++i) {
                int row = row0 + i;
                float v = acc[m][n][i] + bv;
                if constexpr (MODE == 0) {
                    int which = col >> 10;   // 0=q 1=k 2=v
                    int c = col & 1023;
                    int h = c >> 6, d = c & 63;
                    int b = row >> 11, t = row & 2047;
                    if (which == 0) v *= QSCALE;
                    bf16* dst = (bf16*)(which == 0 ? out0 : which == 1 ? out1 : out2);
                    dst[(((size_t)(b * HH + h)) * TT + t) * DD + d] = (bf16)v;
                } else {
                    ((float*)out0)[(size_t)row * N + col] = v;
                }
            }
        }
    }
}

// ---------------- causal flash attention ----------------
// Q,K: bf16 [B*H][T][D] (q pre-scaled by QSCALE). Vt: bf16 [B*H][D][T].
// Y: bf16 [B][T][C] with c = h*64+d.
// 128 q-rows per block, 4 waves x 32 rows, Q in registers, in-register softmax.
__global__ __launch_bounds__(256) void attn_kernel(
    const bf16* __restrict__ Q, const bf16* __restrict__ Kb, const bf16* __restrict__ Vt,
    bf16* __restrict__ Y)
{
    constexpr int PD = 72;
    __shared__ bf16 Ks[64 * PD];   // [key][d]
    __shared__ bf16 Vs[64 * PD];   // [d][key]
    __shared__ bf16 Ps[128 * PD];  // [q_local][key]

    int bh = blockIdx.x;           // 0..63
    int qt = 15 - (int)blockIdx.y; // heavy (high-qt) blocks dispatch first
    int b = bh >> 4, h = bh & 15;

    int tid = threadIdx.x;
    int lane = tid & 63, w = tid >> 6;
    int l15 = lane & 15, l4 = lane >> 4;

    const bf16* Qg = Q  + (size_t)bh * TT * DD;
    const bf16* Kg = Kb + (size_t)bh * TT * DD;
    const bf16* Vg = Vt + (size_t)bh * DD * TT;

    int q0 = qt * 128 + w * 32;    // wave's first q row

    // Q fragments in registers (A-layout: lane l15 = q row, k contiguous)
    bf16x8 qf[2][2];
    #pragma unroll
    for (int m = 0; m < 2; ++m)
        #pragma unroll
        for (int kk = 0; kk < 2; ++kk)
            qf[m][kk] = *(const bf16x8*)(Qg + (size_t)(q0 + m * 16 + l15) * DD + kk * 32 + l4 * 8);

    f32x4 o[2][4] = {};
    float mst[2][4], lst[2][4];
    #pragma unroll
    for (int m = 0; m < 2; ++m)
        #pragma unroll
        for (int i = 0; i < 4; ++i) { mst[m][i] = -1e30f; lst[m][i] = 0.f; }

    int NT = 2 * qt + 2;
    int sr = tid >> 3, sc = (tid & 7) * 8;

    for (int kt = 0; kt < NT; ++kt) {
        __syncthreads();
        // stage K tile [64 keys][64 d] and V^T tile [64 d][64 keys], vectorized
        #pragma unroll
        for (int p = 0; p < 2; ++p) {
            int rr = sr + p * 32;
            *(bf16x8*)(&Ks[rr * PD + sc]) = *(const bf16x8*)(Kg + (size_t)(kt * 64 + rr) * DD + sc);
            *(bf16x8*)(&Vs[rr * PD + sc]) = *(const bf16x8*)(Vg + (size_t)rr * TT + kt * 64 + sc);
        }
        __syncthreads();

        // S = Q @ K^T  (C-layout: col=key=l15(+16n), row=q=l4*4+i(+16m))
        f32x4 s[2][4] = {};
        #pragma unroll
        for (int kk = 0; kk < 2; ++kk) {
            bf16x8 kf[4];
            #pragma unroll
            for (int n = 0; n < 4; ++n)
                kf[n] = *(const bf16x8*)(&Ks[(n * 16 + l15) * PD + kk * 32 + l4 * 8]);
            #pragma unroll
            for (int m = 0; m < 2; ++m)
                #pragma unroll
                for (int n = 0; n < 4; ++n)
                    s[m][n] = __builtin_amdgcn_mfma_f32_16x16x32_bf16(qf[m][kk], kf[n], s[m][n], 0, 0, 0);
        }

        // in-register online softmax (row-parallel across the 16-lane l15 group)
        #pragma unroll
        for (int m = 0; m < 2; ++m) {
            int qrow_base = q0 + m * 16 + l4 * 4;
            if (kt * 64 + 63 > q0 + m * 16) {   // tile may cross the diagonal for this frag
                #pragma unroll
                for (int n = 0; n < 4; ++n) {
                    int key = kt * 64 + n * 16 + l15;
                    #pragma unroll
                    for (int i = 0; i < 4; ++i)
                        if (key > qrow_base + i) s[m][n][i] = -1e30f;
                }
            }
            float mx[4];
            #pragma unroll
            for (int i = 0; i < 4; ++i) {
                mx[i] = fmaxf(fmaxf(s[m][0][i], s[m][1][i]), fmaxf(s[m][2][i], s[m][3][i]));
                mx[i] = fmaxf(mx[i], __shfl_xor(mx[i], 1));
                mx[i] = fmaxf(mx[i], __shfl_xor(mx[i], 2));
                mx[i] = fmaxf(mx[i], __shfl_xor(mx[i], 4));
                mx[i] = fmaxf(mx[i], __shfl_xor(mx[i], 8));
            }
            float rsum[4];
            #pragma unroll
            for (int i = 0; i < 4; ++i) {
                float mnew = fmaxf(mst[m][i], mx[i]);
                float scale = exp2f(mst[m][i] - mnew);
                mst[m][i] = mnew;
                lst[m][i] *= scale;
                rsum[i] = 0.f;
                #pragma unroll
                for (int n = 0; n < 4; ++n) o[m][n][i] *= scale;
            }
            #pragma unroll
            for (int n = 0; n < 4; ++n) {
                #pragma unroll
                for (int i = 0; i < 4; ++i) {
                    float p = exp2f(s[m][n][i] - mst[m][i]);
                    rsum[i] += p;
                    Ps[(w * 32 + m * 16 + l4 * 4 + i) * PD + n * 16 + l15] = (bf16)p;
                }
            }
            #pragma unroll
            for (int i = 0; i < 4; ++i) {
                rsum[i] += __shfl_xor(rsum[i], 1);
                rsum[i] += __shfl_xor(rsum[i], 2);
                rsum[i] += __shfl_xor(rsum[i], 4);
                rsum[i] += __shfl_xor(rsum[i], 8);
                lst[m][i] += rsum[i];
            }
        }

        asm volatile("s_waitcnt lgkmcnt(0)" ::: "memory");
        __builtin_amdgcn_sched_barrier(0);

        // O += P @ V   (P rows are wave-private; Vs staged under barrier)
        #pragma unroll
        for (int kk = 0; kk < 2; ++kk) {
            bf16x8 pf[2], vf[4];
            #pragma unroll
            for (int m = 0; m < 2; ++m)
                pf[m] = *(const bf16x8*)(&Ps[(w * 32 + m * 16 + l15) * PD + kk * 32 + l4 * 8]);
            #pragma unroll
            for (int n = 0; n < 4; ++n)
                vf[n] = *(const bf16x8*)(&Vs[(n * 16 + l15) * PD + kk * 32 + l4 * 8]);
            #pragma unroll
            for (int m = 0; m < 2; ++m)
                #pragma unroll
                for (int n = 0; n < 4; ++n)
                    o[m][n] = __builtin_amdgcn_mfma_f32_16x16x32_bf16(pf[m], vf[n], o[m][n], 0, 0, 0);
        }
    }

    // epilogue: Y[b][t][h*64+d] = o / l
    #pragma unroll
    for (int m = 0; m < 2; ++m) {
        #pragma unroll
        for (int i = 0; i < 4; ++i) {
            float inv = 1.f / lst[m][i];
            int t = q0 + m * 16 + l4 * 4 + i;
            #pragma unroll
            for (int n = 0; n < 4; ++n) {
                int d = n * 16 + l15;
                Y[((size_t)(b * TT + t)) * CC + h * DD + d] = (bf16)(o[m][n][i] * inv);
            }
        }
    }
}

extern "C" void kernel_launch(void* const* d_in, const int* in_sizes, int n_in,
                              void* d_out, int out_size, void* d_ws, size_t ws_size,
                              hipStream_t stream) {
    const float* x      = (const float*)d_in[0];
    const float* w_attn = (const float*)d_in[1];
    const float* b_attn = (const float*)d_in[2];
    const float* w_proj = (const float*)d_in[3];
    const float* b_proj = (const float*)d_in[4];
    float* out = (float*)d_out;

    bf16* xb  = (bf16*)d_ws;                        // [8192][1024]      16 MB
    bf16* waT = xb  + (size_t)MM * CC;              // [3072][1024]       6 MB
    bf16* wpT = waT + (size_t)3 * CC * CC;          // [1024][1024]       2 MB
    bf16* qb  = wpT + (size_t)CC * CC;              // [B*H][T][D]       16 MB
    bf16* kb  = qb  + (size_t)MM * CC;              // [B*H][T][D]       16 MB
    bf16* vb  = kb  + (size_t)MM * CC;              // [B*H][T][D]       16 MB
    bf16* vt  = vb  + (size_t)MM * CC;              // [B*H][D][T]       16 MB
    bf16* yb  = vb;                                 // alias vb (dead after transpose_v)

    conv_f32_bf16<<<2048, 256, 0, stream>>>(x, xb, MM * CC);
    transpose_f32_bf16<<<dim3(3 * CC / 64, CC / 64), 256, 0, stream>>>(w_attn, waT, CC, 3 * CC);
    transpose_f32_bf16<<<dim3(CC / 64, CC / 64), 256, 0, stream>>>(w_proj, wpT, CC, CC);

    gemm_bt<0><<<dim3(3 * CC / 128, MM / 128), 256, 0, stream>>>(
        xb, waT, b_attn, qb, kb, vb, MM, 3 * CC, CC);

    transpose_v<<<dim3(BB * HH, TT / 64), 256, 0, stream>>>(vb, vt);

    attn_kernel<<<dim3(BB * HH, TT / 128), 256, 0, stream>>>(qb, kb, vt, yb);

    gemm_bt<1><<<dim3(CC / 128, MM / 128), 256, 0, stream>>>(
        yb, wpT, b_proj, out, nullptr, nullptr, MM, CC, CC);
}

// Round 3
// 226.421 us; speedup vs baseline: 1.3145x; 1.2010x over previous
//
#include <hip/hip_runtime.h>

typedef __bf16 bf16;
typedef __bf16 bf16x8 __attribute__((ext_vector_type(8)));
typedef __bf16 bf16x4 __attribute__((ext_vector_type(4)));
typedef float f32x4 __attribute__((ext_vector_type(4)));

// Problem constants
#define BB 4
#define TT 2048
#define CC 1024
#define HH 16
#define DD 64
#define MM (BB*TT)   // 8192

// softmax scale folded into q: 1/sqrt(64) * log2(e)  (we use exp2 in the kernel)
#define QSCALE (0.125f * 1.4426950408889634f)

__device__ __forceinline__ void async_copy16(const bf16* g, bf16* l) {
    __builtin_amdgcn_global_load_lds((const __attribute__((address_space(1))) void*)g,
                                     (__attribute__((address_space(3))) void*)l, 16, 0, 0);
}

// ---------------- convert f32 -> bf16 ----------------
__global__ void conv_f32_bf16(const float* __restrict__ in, bf16* __restrict__ out, int n) {
    int i = (blockIdx.x * blockDim.x + threadIdx.x) * 4;
    int stride = gridDim.x * blockDim.x * 4;
    for (; i < n; i += stride) {
        float4 v = *(const float4*)(in + i);
        bf16x4 o;
        o[0] = (bf16)v.x; o[1] = (bf16)v.y; o[2] = (bf16)v.z; o[3] = (bf16)v.w;
        *(bf16x4*)(out + i) = o;
    }
}

// ---------------- transpose + convert: in [K][N] f32 -> out [N][K] bf16 ----------------
__global__ void transpose_f32_bf16(const float* __restrict__ in, bf16* __restrict__ out,
                                   int K, int N) {
    __shared__ bf16 tile[64][65];
    int n0 = blockIdx.x * 64, k0 = blockIdx.y * 64;
    int tc = threadIdx.x & 63, tr = threadIdx.x >> 6;
    #pragma unroll
    for (int p = 0; p < 16; ++p) {
        int k = tr + p * 4;
        tile[k][tc] = (bf16)in[(size_t)(k0 + k) * N + n0 + tc];
    }
    __syncthreads();
    #pragma unroll
    for (int p = 0; p < 16; ++p) {
        int n = tr + p * 4;
        out[(size_t)(n0 + n) * K + k0 + tc] = tile[tc][n];
    }
}

// ---------------- bf16 transpose: [bh][t][d] -> [bh][d][t] ----------------
__global__ void transpose_v(const bf16* __restrict__ in, bf16* __restrict__ out) {
    __shared__ bf16 tile[64][72];
    int bh = blockIdx.x;
    int t0 = blockIdx.y * 64;
    int r = threadIdx.x >> 3, c = (threadIdx.x & 7) * 8;
    const bf16* src = in + ((size_t)bh * TT + t0) * DD;
    #pragma unroll
    for (int p = 0; p < 2; ++p) {
        int rr = r + p * 32;
        *(bf16x8*)(&tile[rr][c]) = *(const bf16x8*)(src + rr * DD + c);
    }
    __syncthreads();
    bf16* dst = out + (size_t)bh * DD * TT + t0;
    #pragma unroll
    for (int p = 0; p < 2; ++p) {
        int d = r + p * 32;
        bf16x8 v;
        #pragma unroll
        for (int j = 0; j < 8; ++j) v[j] = tile[c + j][d];
        *(bf16x8*)(dst + (size_t)d * TT + c) = v;
    }
}

// ---------------- GEMM: C[M][N] = A[M][K] @ Bt[N][K]^T + bias ----------------
template<int MODE>
__global__ __launch_bounds__(256) void gemm_bt(
    const bf16* __restrict__ A, const bf16* __restrict__ Bt,
    const float* __restrict__ bias,
    void* __restrict__ out0, void* __restrict__ out1, void* __restrict__ out2,
    int M, int N, int K)
{
    constexpr int BM = 128, BN = 128, BK = 64;
    __shared__ bf16 As[BM * BK];
    __shared__ bf16 Bs[BN * BK];

    int bx = blockIdx.x, by = blockIdx.y;
    int tid = threadIdx.x;
    int lane = tid & 63, wave = tid >> 6;
    int wr = wave >> 1, wc = wave & 1;
    int l15 = lane & 15, l4 = lane >> 4;

    const bf16* Ab = A + (size_t)(by * BM) * K;
    const bf16* Bb = Bt + (size_t)(bx * BN) * K;

    f32x4 acc[4][4] = {};

    int lrow = lane >> 3;         // 0..7
    int lcol = (lane & 7) * 8;    // 0..56

    for (int k0 = 0; k0 < K; k0 += BK) {
        __syncthreads();
        #pragma unroll
        for (int j = 0; j < 4; ++j) {
            int rbase = j * 32 + wave * 8;
            int r = rbase + lrow;
            async_copy16(Ab + (size_t)r * K + k0 + lcol, &As[rbase * BK]);
            async_copy16(Bb + (size_t)r * K + k0 + lcol, &Bs[rbase * BK]);
        }
        asm volatile("s_waitcnt vmcnt(0)" ::: "memory");
        __syncthreads();
        #pragma unroll
        for (int kk = 0; kk < 2; ++kk) {
            bf16x8 af[4], bf_[4];
            #pragma unroll
            for (int m = 0; m < 4; ++m)
                af[m] = *(const bf16x8*)(&As[(wr * 64 + m * 16 + l15) * BK + kk * 32 + l4 * 8]);
            #pragma unroll
            for (int n = 0; n < 4; ++n)
                bf_[n] = *(const bf16x8*)(&Bs[(wc * 64 + n * 16 + l15) * BK + kk * 32 + l4 * 8]);
            #pragma unroll
            for (int m = 0; m < 4; ++m)
                #pragma unroll
                for (int n = 0; n < 4; ++n)
                    acc[m][n] = __builtin_amdgcn_mfma_f32_16x16x32_bf16(af[m], bf_[n], acc[m][n], 0, 0, 0);
        }
    }

    #pragma unroll
    for (int m = 0; m < 4; ++m) {
        #pragma unroll
        for (int n = 0; n < 4; ++n) {
            int row0 = by * BM + wr * 64 + m * 16 + l4 * 4;
            int col  = bx * BN + wc * 64 + n * 16 + l15;
            float bv = bias[col];
            #pragma unroll
            for (int i = 0; i < 4; ++i) {
                int row = row0 + i;
                float v = acc[m][n][i] + bv;
                if constexpr (MODE == 0) {
                    int which = col >> 10;   // 0=q 1=k 2=v
                    int c = col & 1023;
                    int h = c >> 6, d = c & 63;
                    int b = row >> 11, t = row & 2047;
                    if (which == 0) v *= QSCALE;
                    bf16* dst = (bf16*)(which == 0 ? out0 : which == 1 ? out1 : out2);
                    dst[(((size_t)(b * HH + h)) * TT + t) * DD + d] = (bf16)v;
                } else {
                    ((float*)out0)[(size_t)row * N + col] = v;
                }
            }
        }
    }
}

// ---------------- causal flash attention (swapped-QK, dbuf, defer-max) ----------------
// Q,K: bf16 [B*H][T][D] (q pre-scaled by QSCALE). Vt: bf16 [B*H][D][T].
// Y: bf16 [B][T][C] with c = h*64+d.
// 128 q-rows/block, 4 waves x 32 rows. Swapped QK^T: s = mfma(K, Q) so
// s[ms][n][i]: q-row = q0+ms*16+l15, key = kt*64+n*16+l4*4+i  (row state is lane-local).
__global__ __launch_bounds__(256) void attn_kernel(
    const bf16* __restrict__ Q, const bf16* __restrict__ Kb, const bf16* __restrict__ Vt,
    bf16* __restrict__ Y)
{
    constexpr int PD = 72;
    __shared__ bf16 Ks[2][64 * PD];   // [key][d]
    __shared__ bf16 Vs[2][64 * PD];   // [d][key]
    __shared__ bf16 Ps[128 * PD];     // [q_local][key]

    int bh = blockIdx.x;           // 0..63
    int qt = 15 - (int)blockIdx.y; // heavy blocks dispatch first
    int b = bh >> 4, h = bh & 15;

    int tid = threadIdx.x;
    int lane = tid & 63, w = tid >> 6;
    int l15 = lane & 15, l4 = lane >> 4;

    const bf16* Qg = Q  + (size_t)bh * TT * DD;
    const bf16* Kg = Kb + (size_t)bh * TT * DD;
    const bf16* Vg = Vt + (size_t)bh * DD * TT;

    int q0 = qt * 128 + w * 32;    // wave's first q row

    // Q fragments (same lane layout serves as the MFMA B-operand)
    bf16x8 qf[2][2];
    #pragma unroll
    for (int m = 0; m < 2; ++m)
        #pragma unroll
        for (int kk = 0; kk < 2; ++kk)
            qf[m][kk] = *(const bf16x8*)(Qg + (size_t)(q0 + m * 16 + l15) * DD + kk * 32 + l4 * 8);

    f32x4 o[2][4] = {};                 // o[mq][n]: q = q0+mq*16+l4*4+i, d = n*16+l15
    float mst[2] = {-1e30f, -1e30f};    // per q-row (ms, l15)
    float lst[2] = {0.f, 0.f};

    int NT = 2 * qt + 2;
    int sr = tid >> 3, sc = (tid & 7) * 8;

    // prologue: load tile 0 into regs
    bf16x8 kr0 = *(const bf16x8*)(Kg + (size_t)sr * DD + sc);
    bf16x8 kr1 = *(const bf16x8*)(Kg + (size_t)(sr + 32) * DD + sc);
    bf16x8 vr0 = *(const bf16x8*)(Vg + (size_t)sr * TT + sc);
    bf16x8 vr1 = *(const bf16x8*)(Vg + (size_t)(sr + 32) * TT + sc);

    for (int kt = 0; kt < NT; ++kt) {
        int buf = kt & 1;
        // write staged regs to LDS buffer
        *(bf16x8*)(&Ks[buf][(size_t)sr * PD + sc])        = kr0;
        *(bf16x8*)(&Ks[buf][(size_t)(sr + 32) * PD + sc]) = kr1;
        *(bf16x8*)(&Vs[buf][(size_t)sr * PD + sc])        = vr0;
        *(bf16x8*)(&Vs[buf][(size_t)(sr + 32) * PD + sc]) = vr1;
        // issue next tile's global loads (latency hides under this tile's compute)
        if (kt + 1 < NT) {
            const bf16* kp = Kg + (size_t)((kt + 1) * 64 + sr) * DD + sc;
            kr0 = *(const bf16x8*)(kp);
            kr1 = *(const bf16x8*)(kp + 32 * DD);
            const bf16* vp = Vg + (size_t)sr * TT + (kt + 1) * 64 + sc;
            vr0 = *(const bf16x8*)(vp);
            vr1 = *(const bf16x8*)(vp + (size_t)32 * TT);
        }
        __syncthreads();

        if (kt * 64 <= q0 + 31) {      // wave has unmasked rows in this tile
            int ktb = kt * 64;
            // S^T = K @ Q^T
            f32x4 s[2][4] = {};
            #pragma unroll
            for (int kk = 0; kk < 2; ++kk) {
                bf16x8 kf[4];
                #pragma unroll
                for (int n = 0; n < 4; ++n)
                    kf[n] = *(const bf16x8*)(&Ks[buf][(n * 16 + l15) * PD + kk * 32 + l4 * 8]);
                #pragma unroll
                for (int ms = 0; ms < 2; ++ms)
                    #pragma unroll
                    for (int n = 0; n < 4; ++n)
                        s[ms][n] = __builtin_amdgcn_mfma_f32_16x16x32_bf16(kf[n], qf[ms][kk], s[ms][n], 0, 0, 0);
            }

            #pragma unroll
            for (int ms = 0; ms < 2; ++ms) {
                int qr = q0 + ms * 16 + l15;
                if (ktb + 63 > q0 + ms * 16) {   // tile crosses diagonal for this frag
                    #pragma unroll
                    for (int n = 0; n < 4; ++n) {
                        int keyb = ktb + n * 16 + l4 * 4;
                        #pragma unroll
                        for (int i = 0; i < 4; ++i)
                            if (keyb + i > qr) s[ms][n][i] = -1e30f;
                    }
                }
                // in-lane row max (16 vals) + 2 shuffles across l4 groups
                float mx0 = fmaxf(fmaxf(s[ms][0][0], s[ms][0][1]), fmaxf(s[ms][0][2], s[ms][0][3]));
                float mx1 = fmaxf(fmaxf(s[ms][1][0], s[ms][1][1]), fmaxf(s[ms][1][2], s[ms][1][3]));
                float mx2 = fmaxf(fmaxf(s[ms][2][0], s[ms][2][1]), fmaxf(s[ms][2][2], s[ms][2][3]));
                float mx3 = fmaxf(fmaxf(s[ms][3][0], s[ms][3][1]), fmaxf(s[ms][3][2], s[ms][3][3]));
                float mx = fmaxf(fmaxf(mx0, mx1), fmaxf(mx2, mx3));
                mx = fmaxf(mx, __shfl_xor(mx, 16));
                mx = fmaxf(mx, __shfl_xor(mx, 32));

                // defer-max: only rescale when the max grew by more than 11.5 (log2)
                if (__any(mx > mst[ms] + 11.5f)) {
                    float mnew = fmaxf(mst[ms], mx);
                    float sc2 = exp2f(mst[ms] - mnew);
                    mst[ms] = mnew;
                    lst[ms] *= sc2;
                    float scl[4];
                    #pragma unroll
                    for (int i = 0; i < 4; ++i) scl[i] = __shfl(sc2, l4 * 4 + i);
                    #pragma unroll
                    for (int n = 0; n < 4; ++n)
                        #pragma unroll
                        for (int i = 0; i < 4; ++i) o[ms][n][i] *= scl[i];
                }

                float rs = 0.f;
                #pragma unroll
                for (int n = 0; n < 4; ++n) {
                    bf16x4 pk;
                    #pragma unroll
                    for (int i = 0; i < 4; ++i) {
                        float p = exp2f(s[ms][n][i] - mst[ms]);
                        rs += p;
                        pk[i] = (bf16)p;
                    }
                    *(bf16x4*)(&Ps[(w * 32 + ms * 16 + l15) * PD + n * 16 + l4 * 4]) = pk;
                }
                rs += __shfl_xor(rs, 16);
                rs += __shfl_xor(rs, 32);
                lst[ms] += rs;
            }

            asm volatile("s_waitcnt lgkmcnt(0)" ::: "memory");
            __builtin_amdgcn_sched_barrier(0);

            // O += P @ V   (P rows are wave-private)
            #pragma unroll
            for (int kk = 0; kk < 2; ++kk) {
                bf16x8 pf[2], vf[4];
                #pragma unroll
                for (int mq = 0; mq < 2; ++mq)
                    pf[mq] = *(const bf16x8*)(&Ps[(w * 32 + mq * 16 + l15) * PD + kk * 32 + l4 * 8]);
                #pragma unroll
                for (int n = 0; n < 4; ++n)
                    vf[n] = *(const bf16x8*)(&Vs[buf][(n * 16 + l15) * PD + kk * 32 + l4 * 8]);
                #pragma unroll
                for (int mq = 0; mq < 2; ++mq)
                    #pragma unroll
                    for (int n = 0; n < 4; ++n)
                        o[mq][n] = __builtin_amdgcn_mfma_f32_16x16x32_bf16(pf[mq], vf[n], o[mq][n], 0, 0, 0);
            }
        }
    }

    // epilogue: Y[b][t][h*64+d] = o / l   (broadcast l from s-layout lanes)
    #pragma unroll
    for (int mq = 0; mq < 2; ++mq) {
        float inv[4];
        #pragma unroll
        for (int i = 0; i < 4; ++i) inv[i] = 1.f / __shfl(lst[mq], l4 * 4 + i);
        #pragma unroll
        for (int i = 0; i < 4; ++i) {
            int t = q0 + mq * 16 + l4 * 4 + i;
            #pragma unroll
            for (int n = 0; n < 4; ++n) {
                int d = n * 16 + l15;
                Y[((size_t)(b * TT + t)) * CC + h * DD + d] = (bf16)(o[mq][n][i] * inv[i]);
            }
        }
    }
}

extern "C" void kernel_launch(void* const* d_in, const int* in_sizes, int n_in,
                              void* d_out, int out_size, void* d_ws, size_t ws_size,
                              hipStream_t stream) {
    const float* x      = (const float*)d_in[0];
    const float* w_attn = (const float*)d_in[1];
    const float* b_attn = (const float*)d_in[2];
    const float* w_proj = (const float*)d_in[3];
    const float* b_proj = (const float*)d_in[4];
    float* out = (float*)d_out;

    bf16* xb  = (bf16*)d_ws;                        // [8192][1024]
    bf16* waT = xb  + (size_t)MM * CC;              // [3072][1024]
    bf16* wpT = waT + (size_t)3 * CC * CC;          // [1024][1024]
    bf16* qb  = wpT + (size_t)CC * CC;              // [B*H][T][D]
    bf16* kb  = qb  + (size_t)MM * CC;              // [B*H][T][D]
    bf16* vb  = kb  + (size_t)MM * CC;              // [B*H][T][D]
    bf16* vt  = vb  + (size_t)MM * CC;              // [B*H][D][T]
    bf16* yb  = vb;                                 // alias vb (dead after transpose_v)

    conv_f32_bf16<<<2048, 256, 0, stream>>>(x, xb, MM * CC);
    transpose_f32_bf16<<<dim3(3 * CC / 64, CC / 64), 256, 0, stream>>>(w_attn, waT, CC, 3 * CC);
    transpose_f32_bf16<<<dim3(CC / 64, CC / 64), 256, 0, stream>>>(w_proj, wpT, CC, CC);

    gemm_bt<0><<<dim3(3 * CC / 128, MM / 128), 256, 0, stream>>>(
        xb, waT, b_attn, qb, kb, vb, MM, 3 * CC, CC);

    transpose_v<<<dim3(BB * HH, TT / 64), 256, 0, stream>>>(vb, vt);

    attn_kernel<<<dim3(BB * HH, TT / 128), 256, 0, stream>>>(qb, kb, vt, yb);

    gemm_bt<1><<<dim3(CC / 128, MM / 128), 256, 0, stream>>>(
        yb, wpT, b_proj, out, nullptr, nullptr, MM, CC, CC);
}

// Round 4
// 205.897 us; speedup vs baseline: 1.4455x; 1.0997x over previous
//
#include <hip/hip_runtime.h>

typedef __bf16 bf16;
typedef __bf16 bf16x8 __attribute__((ext_vector_type(8)));
typedef __bf16 bf16x4 __attribute__((ext_vector_type(4)));
typedef float f32x4 __attribute__((ext_vector_type(4)));
typedef unsigned int uint;

// Problem constants
#define BB 4
#define TT 2048
#define CC 1024
#define HH 16
#define DD 64
#define MM (BB*TT)   // 8192

// softmax scale folded into q: 1/sqrt(64) * log2(e)  (we use exp2 in the kernel)
#define QSCALE (0.125f * 1.4426950408889634f)

__device__ __forceinline__ void async_copy16(const bf16* g, bf16* l) {
    __builtin_amdgcn_global_load_lds((const __attribute__((address_space(1))) void*)g,
                                     (__attribute__((address_space(3))) void*)l, 16, 0, 0);
}

// ---------------- convert f32 -> bf16 ----------------
__global__ void conv_f32_bf16(const float* __restrict__ in, bf16* __restrict__ out, int n) {
    int i = (blockIdx.x * blockDim.x + threadIdx.x) * 4;
    int stride = gridDim.x * blockDim.x * 4;
    for (; i < n; i += stride) {
        float4 v = *(const float4*)(in + i);
        bf16x4 o;
        o[0] = (bf16)v.x; o[1] = (bf16)v.y; o[2] = (bf16)v.z; o[3] = (bf16)v.w;
        *(bf16x4*)(out + i) = o;
    }
}

// ---------------- transpose + convert: in [K][N] f32 -> out [N][K] bf16 ----------------
__global__ void transpose_f32_bf16(const float* __restrict__ in, bf16* __restrict__ out,
                                   int K, int N) {
    __shared__ bf16 tile[64][65];
    int n0 = blockIdx.x * 64, k0 = blockIdx.y * 64;
    int tc = threadIdx.x & 63, tr = threadIdx.x >> 6;
    #pragma unroll
    for (int p = 0; p < 16; ++p) {
        int k = tr + p * 4;
        tile[k][tc] = (bf16)in[(size_t)(k0 + k) * N + n0 + tc];
    }
    __syncthreads();
    #pragma unroll
    for (int p = 0; p < 16; ++p) {
        int n = tr + p * 4;
        out[(size_t)(n0 + n) * K + k0 + tc] = tile[tc][n];
    }
}

// ---------------- bf16 transpose: [bh][t][d] -> [bh][d][t] ----------------
__global__ void transpose_v(const bf16* __restrict__ in, bf16* __restrict__ out) {
    __shared__ bf16 tile[64][72];
    int bh = blockIdx.x;
    int t0 = blockIdx.y * 64;
    int r = threadIdx.x >> 3, c = (threadIdx.x & 7) * 8;
    const bf16* src = in + ((size_t)bh * TT + t0) * DD;
    #pragma unroll
    for (int p = 0; p < 2; ++p) {
        int rr = r + p * 32;
        *(bf16x8*)(&tile[rr][c]) = *(const bf16x8*)(src + rr * DD + c);
    }
    __syncthreads();
    bf16* dst = out + (size_t)bh * DD * TT + t0;
    #pragma unroll
    for (int p = 0; p < 2; ++p) {
        int d = r + p * 32;
        bf16x8 v;
        #pragma unroll
        for (int j = 0; j < 8; ++j) v[j] = tile[c + j][d];
        *(bf16x8*)(dst + (size_t)d * TT + c) = v;
    }
}

// ---------------- GEMM: C[M][N] = A[M][K] @ Bt[N][K]^T + bias ----------------
template<int MODE>
__global__ __launch_bounds__(256) void gemm_bt(
    const bf16* __restrict__ A, const bf16* __restrict__ Bt,
    const float* __restrict__ bias,
    void* __restrict__ out0, void* __restrict__ out1, void* __restrict__ out2,
    int M, int N, int K)
{
    constexpr int BM = 128, BN = 128, BK = 64;
    __shared__ bf16 As[BM * BK];
    __shared__ bf16 Bs[BN * BK];

    int bx = blockIdx.x, by = blockIdx.y;
    int tid = threadIdx.x;
    int lane = tid & 63, wave = tid >> 6;
    int wr = wave >> 1, wc = wave & 1;
    int l15 = lane & 15, l4 = lane >> 4;

    const bf16* Ab = A + (size_t)(by * BM) * K;
    const bf16* Bb = Bt + (size_t)(bx * BN) * K;

    f32x4 acc[4][4] = {};

    int lrow = lane >> 3;         // 0..7
    int lcol = (lane & 7) * 8;    // 0..56

    for (int k0 = 0; k0 < K; k0 += BK) {
        __syncthreads();
        #pragma unroll
        for (int j = 0; j < 4; ++j) {
            int rbase = j * 32 + wave * 8;
            int r = rbase + lrow;
            async_copy16(Ab + (size_t)r * K + k0 + lcol, &As[rbase * BK]);
            async_copy16(Bb + (size_t)r * K + k0 + lcol, &Bs[rbase * BK]);
        }
        asm volatile("s_waitcnt vmcnt(0)" ::: "memory");
        __syncthreads();
        #pragma unroll
        for (int kk = 0; kk < 2; ++kk) {
            bf16x8 af[4], bf_[4];
            #pragma unroll
            for (int m = 0; m < 4; ++m)
                af[m] = *(const bf16x8*)(&As[(wr * 64 + m * 16 + l15) * BK + kk * 32 + l4 * 8]);
            #pragma unroll
            for (int n = 0; n < 4; ++n)
                bf_[n] = *(const bf16x8*)(&Bs[(wc * 64 + n * 16 + l15) * BK + kk * 32 + l4 * 8]);
            #pragma unroll
            for (int m = 0; m < 4; ++m)
                #pragma unroll
                for (int n = 0; n < 4; ++n)
                    acc[m][n] = __builtin_amdgcn_mfma_f32_16x16x32_bf16(af[m], bf_[n], acc[m][n], 0, 0, 0);
        }
    }

    #pragma unroll
    for (int m = 0; m < 4; ++m) {
        #pragma unroll
        for (int n = 0; n < 4; ++n) {
            int row0 = by * BM + wr * 64 + m * 16 + l4 * 4;
            int col  = bx * BN + wc * 64 + n * 16 + l15;
            float bv = bias[col];
            #pragma unroll
            for (int i = 0; i < 4; ++i) {
                int row = row0 + i;
                float v = acc[m][n][i] + bv;
                if constexpr (MODE == 0) {
                    int which = col >> 10;   // 0=q 1=k 2=v
                    int c = col & 1023;
                    int h = c >> 6, d = c & 63;
                    int b = row >> 11, t = row & 2047;
                    if (which == 0) v *= QSCALE;
                    bf16* dst = (bf16*)(which == 0 ? out0 : which == 1 ? out1 : out2);
                    dst[(((size_t)(b * HH + h)) * TT + t) * DD + d] = (bf16)v;
                } else {
                    ((float*)out0)[(size_t)row * N + col] = v;
                }
            }
        }
    }
}

// ---------------- causal flash attention (swapped-QK, dbuf, defer-max, in-reg P) ----------------
// Q,K: bf16 [B*H][T][D] (q pre-scaled by QSCALE). Vt: bf16 [B*H][D][T].
// Y: bf16 [B][T][C] with c = h*64+d.
// 128 q-rows/block, 4 waves x 32 rows. Swapped QK^T: s = mfma(K, Q) so
// s[ms][n][i]: q-row = q0+ms*16+l15, key = kt*64+n*16+l4*4+i  (row state is lane-local).
// P never touches LDS: pack to bf16 pairs (cvt_pk), then a 2-stage butterfly
// (permlane32_swap over the (pk0,pk1)/(pk2,pk3) pairs, then permlane16_swap)
// lands the PV A-fragment layout (lane l15 = q, elems = keys kk*32+l4*8..+7).
__global__ __launch_bounds__(256, 3) void attn_kernel(
    const bf16* __restrict__ Q, const bf16* __restrict__ Kb, const bf16* __restrict__ Vt,
    bf16* __restrict__ Y)
{
    constexpr int PD = 72;
    __shared__ bf16 Ks[2][64 * PD];   // [key][d]
    __shared__ bf16 Vs[2][64 * PD];   // [d][key]

    int bh = blockIdx.x;           // 0..63
    int qt = 15 - (int)blockIdx.y; // heavy blocks dispatch first
    int b = bh >> 4, h = bh & 15;

    int tid = threadIdx.x;
    int lane = tid & 63, w = tid >> 6;
    int l15 = lane & 15, l4 = lane >> 4;

    const bf16* Qg = Q  + (size_t)bh * TT * DD;
    const bf16* Kg = Kb + (size_t)bh * TT * DD;
    const bf16* Vg = Vt + (size_t)bh * DD * TT;

    int q0 = qt * 128 + w * 32;    // wave's first q row

    // Q fragments (serve as the MFMA B-operand in the swapped QK^T)
    bf16x8 qf[2][2];
    #pragma unroll
    for (int m = 0; m < 2; ++m)
        #pragma unroll
        for (int kk = 0; kk < 2; ++kk)
            qf[m][kk] = *(const bf16x8*)(Qg + (size_t)(q0 + m * 16 + l15) * DD + kk * 32 + l4 * 8);

    f32x4 o[2][4] = {};                 // o[mq][n]: q = q0+mq*16+l4*4+i, d = n*16+l15
    float mst[2] = {-1e30f, -1e30f};    // per q-row (ms, l15)
    float lst[2] = {0.f, 0.f};

    int NT = 2 * qt + 2;
    int sr = tid >> 3, sc = (tid & 7) * 8;

    // prologue: load tile 0 into regs
    bf16x8 kr0 = *(const bf16x8*)(Kg + (size_t)sr * DD + sc);
    bf16x8 kr1 = *(const bf16x8*)(Kg + (size_t)(sr + 32) * DD + sc);
    bf16x8 vr0 = *(const bf16x8*)(Vg + (size_t)sr * TT + sc);
    bf16x8 vr1 = *(const bf16x8*)(Vg + (size_t)(sr + 32) * TT + sc);

    for (int kt = 0; kt < NT; ++kt) {
        int buf = kt & 1;
        // write staged regs to LDS buffer
        *(bf16x8*)(&Ks[buf][(size_t)sr * PD + sc])        = kr0;
        *(bf16x8*)(&Ks[buf][(size_t)(sr + 32) * PD + sc]) = kr1;
        *(bf16x8*)(&Vs[buf][(size_t)sr * PD + sc])        = vr0;
        *(bf16x8*)(&Vs[buf][(size_t)(sr + 32) * PD + sc]) = vr1;
        // issue next tile's global loads (latency hides under this tile's compute)
        if (kt + 1 < NT) {
            const bf16* kp = Kg + (size_t)((kt + 1) * 64 + sr) * DD + sc;
            kr0 = *(const bf16x8*)(kp);
            kr1 = *(const bf16x8*)(kp + 32 * DD);
            const bf16* vp = Vg + (size_t)sr * TT + (kt + 1) * 64 + sc;
            vr0 = *(const bf16x8*)(vp);
            vr1 = *(const bf16x8*)(vp + (size_t)32 * TT);
        }
        __syncthreads();

        if (kt * 64 <= q0 + 31) {      // wave has unmasked rows in this tile
            int ktb = kt * 64;
            // S^T = K @ Q^T
            f32x4 s[2][4] = {};
            #pragma unroll
            for (int kk = 0; kk < 2; ++kk) {
                bf16x8 kf[4];
                #pragma unroll
                for (int n = 0; n < 4; ++n)
                    kf[n] = *(const bf16x8*)(&Ks[buf][(n * 16 + l15) * PD + kk * 32 + l4 * 8]);
                #pragma unroll
                for (int ms = 0; ms < 2; ++ms)
                    #pragma unroll
                    for (int n = 0; n < 4; ++n)
                        s[ms][n] = __builtin_amdgcn_mfma_f32_16x16x32_bf16(kf[n], qf[ms][kk], s[ms][n], 0, 0, 0);
            }

            bf16x8 paf[2][2];   // PV A-fragments, built fully in-register
            #pragma unroll
            for (int ms = 0; ms < 2; ++ms) {
                int qr = q0 + ms * 16 + l15;
                if (ktb + 63 > q0 + ms * 16) {   // tile crosses diagonal for this frag
                    #pragma unroll
                    for (int n = 0; n < 4; ++n) {
                        int keyb = ktb + n * 16 + l4 * 4;
                        #pragma unroll
                        for (int i = 0; i < 4; ++i)
                            if (keyb + i > qr) s[ms][n][i] = -1e30f;
                    }
                }
                // in-lane row max (16 vals) + 2 shuffles across l4 groups
                float mx0 = fmaxf(fmaxf(s[ms][0][0], s[ms][0][1]), fmaxf(s[ms][0][2], s[ms][0][3]));
                float mx1 = fmaxf(fmaxf(s[ms][1][0], s[ms][1][1]), fmaxf(s[ms][1][2], s[ms][1][3]));
                float mx2 = fmaxf(fmaxf(s[ms][2][0], s[ms][2][1]), fmaxf(s[ms][2][2], s[ms][2][3]));
                float mx3 = fmaxf(fmaxf(s[ms][3][0], s[ms][3][1]), fmaxf(s[ms][3][2], s[ms][3][3]));
                float mx = fmaxf(fmaxf(mx0, mx1), fmaxf(mx2, mx3));
                mx = fmaxf(mx, __shfl_xor(mx, 16));
                mx = fmaxf(mx, __shfl_xor(mx, 32));

                // defer-max: only rescale when the max grew by more than 11.5 (log2)
                if (__any(mx > mst[ms] + 11.5f)) {
                    float mnew = fmaxf(mst[ms], mx);
                    float sc2 = exp2f(mst[ms] - mnew);
                    mst[ms] = mnew;
                    lst[ms] *= sc2;
                    float scl[4];
                    #pragma unroll
                    for (int i = 0; i < 4; ++i) scl[i] = __shfl(sc2, l4 * 4 + i);
                    #pragma unroll
                    for (int n = 0; n < 4; ++n)
                        #pragma unroll
                        for (int i = 0; i < 4; ++i) o[ms][n][i] *= scl[i];
                }

                // exp2 + pack to bf16 pairs: pk[n][b] = keys n*16+l4*4+2b..+1 (q = l15)
                uint pk_[4][2];
                float rs = 0.f;
                #pragma unroll
                for (int n = 0; n < 4; ++n) {
                    float p0 = exp2f(s[ms][n][0] - mst[ms]);
                    float p1 = exp2f(s[ms][n][1] - mst[ms]);
                    float p2 = exp2f(s[ms][n][2] - mst[ms]);
                    float p3 = exp2f(s[ms][n][3] - mst[ms]);
                    rs += (p0 + p1) + (p2 + p3);
                    asm("v_cvt_pk_bf16_f32 %0, %1, %2" : "=v"(pk_[n][0]) : "v"(p0), "v"(p1));
                    asm("v_cvt_pk_bf16_f32 %0, %1, %2" : "=v"(pk_[n][1]) : "v"(p2), "v"(p3));
                }
                rs += __shfl_xor(rs, 16);
                rs += __shfl_xor(rs, 32);
                lst[ms] += rs;

                // stage A: cross lane±32.  After: pk_[0]=A (low:own pk0, high:low's pk1),
                // pk_[1]=B (low: high's pk0, high: own pk1); same for (pk2,pk3)->(C,D).
                asm("v_permlane32_swap_b32 %0, %1" : "+v"(pk_[0][0]), "+v"(pk_[1][0]));
                asm("v_permlane32_swap_b32 %0, %1" : "+v"(pk_[0][1]), "+v"(pk_[1][1]));
                asm("v_permlane32_swap_b32 %0, %1" : "+v"(pk_[2][0]), "+v"(pk_[3][0]));
                asm("v_permlane32_swap_b32 %0, %1" : "+v"(pk_[2][1]), "+v"(pk_[3][1]));
                // stage B: cross lane±16.  Outputs are exactly pf[kk].dw[b] / dw[2+b].
                asm("v_permlane16_swap_b32 %0, %1" : "+v"(pk_[0][0]), "+v"(pk_[1][0]));
                asm("v_permlane16_swap_b32 %0, %1" : "+v"(pk_[0][1]), "+v"(pk_[1][1]));
                asm("v_permlane16_swap_b32 %0, %1" : "+v"(pk_[2][0]), "+v"(pk_[3][0]));
                asm("v_permlane16_swap_b32 %0, %1" : "+v"(pk_[2][1]), "+v"(pk_[3][1]));
                uint4 u0 = {pk_[0][0], pk_[0][1], pk_[1][0], pk_[1][1]};
                uint4 u1 = {pk_[2][0], pk_[2][1], pk_[3][0], pk_[3][1]};
                paf[ms][0] = __builtin_bit_cast(bf16x8, u0);
                paf[ms][1] = __builtin_bit_cast(bf16x8, u1);
            }

            // O += P @ V   (P fragments in registers; Vs covered by the tile barrier)
            #pragma unroll
            for (int kk = 0; kk < 2; ++kk) {
                bf16x8 vf[4];
                #pragma unroll
                for (int n = 0; n < 4; ++n)
                    vf[n] = *(const bf16x8*)(&Vs[buf][(n * 16 + l15) * PD + kk * 32 + l4 * 8]);
                #pragma unroll
                for (int mq = 0; mq < 2; ++mq)
                    #pragma unroll
                    for (int n = 0; n < 4; ++n)
                        o[mq][n] = __builtin_amdgcn_mfma_f32_16x16x32_bf16(paf[mq][kk], vf[n], o[mq][n], 0, 0, 0);
            }
        }
    }

    // epilogue: Y[b][t][h*64+d] = o / l   (broadcast l from s-layout lanes)
    #pragma unroll
    for (int mq = 0; mq < 2; ++mq) {
        float inv[4];
        #pragma unroll
        for (int i = 0; i < 4; ++i) inv[i] = 1.f / __shfl(lst[mq], l4 * 4 + i);
        #pragma unroll
        for (int i = 0; i < 4; ++i) {
            int t = q0 + mq * 16 + l4 * 4 + i;
            #pragma unroll
            for (int n = 0; n < 4; ++n) {
                int d = n * 16 + l15;
                Y[((size_t)(b * TT + t)) * CC + h * DD + d] = (bf16)(o[mq][n][i] * inv[i]);
            }
        }
    }
}

extern "C" void kernel_launch(void* const* d_in, const int* in_sizes, int n_in,
                              void* d_out, int out_size, void* d_ws, size_t ws_size,
                              hipStream_t stream) {
    const float* x      = (const float*)d_in[0];
    const float* w_attn = (const float*)d_in[1];
    const float* b_attn = (const float*)d_in[2];
    const float* w_proj = (const float*)d_in[3];
    const float* b_proj = (const float*)d_in[4];
    float* out = (float*)d_out;

    bf16* xb  = (bf16*)d_ws;                        // [8192][1024]
    bf16* waT = xb  + (size_t)MM * CC;              // [3072][1024]
    bf16* wpT = waT + (size_t)3 * CC * CC;          // [1024][1024]
    bf16* qb  = wpT + (size_t)CC * CC;              // [B*H][T][D]
    bf16* kb  = qb  + (size_t)MM * CC;              // [B*H][T][D]
    bf16* vb  = kb  + (size_t)MM * CC;              // [B*H][T][D]
    bf16* vt  = vb  + (size_t)MM * CC;              // [B*H][D][T]
    bf16* yb  = vb;                                 // alias vb (dead after transpose_v)

    conv_f32_bf16<<<2048, 256, 0, stream>>>(x, xb, MM * CC);
    transpose_f32_bf16<<<dim3(3 * CC / 64, CC / 64), 256, 0, stream>>>(w_attn, waT, CC, 3 * CC);
    transpose_f32_bf16<<<dim3(CC / 64, CC / 64), 256, 0, stream>>>(w_proj, wpT, CC, CC);

    gemm_bt<0><<<dim3(3 * CC / 128, MM / 128), 256, 0, stream>>>(
        xb, waT, b_attn, qb, kb, vb, MM, 3 * CC, CC);

    transpose_v<<<dim3(BB * HH, TT / 64), 256, 0, stream>>>(vb, vt);

    attn_kernel<<<dim3(BB * HH, TT / 128), 256, 0, stream>>>(qb, kb, vt, yb);

    gemm_bt<1><<<dim3(CC / 128, MM / 128), 256, 0, stream>>>(
        yb, wpT, b_proj, out, nullptr, nullptr, MM, CC, CC);
}

// Round 5
// 192.594 us; speedup vs baseline: 1.5454x; 1.0691x over previous
//
#include <hip/hip_runtime.h>

typedef __bf16 bf16;
typedef __bf16 bf16x8 __attribute__((ext_vector_type(8)));
typedef __bf16 bf16x4 __attribute__((ext_vector_type(4)));
typedef float f32x4 __attribute__((ext_vector_type(4)));
typedef unsigned int uint;

// Problem constants
#define BB 4
#define TT 2048
#define CC 1024
#define HH 16
#define DD 64
#define MM (BB*TT)   // 8192

// softmax scale folded into q: 1/sqrt(64) * log2(e)  (we use exp2 in the kernel)
#define QSCALE (0.125f * 1.4426950408889634f)

__device__ __forceinline__ void async_copy16(const bf16* g, bf16* l) {
    __builtin_amdgcn_global_load_lds((const __attribute__((address_space(1))) void*)g,
                                     (__attribute__((address_space(3))) void*)l, 16, 0, 0);
}

// ---------------- convert f32 -> bf16 ----------------
__global__ void conv_f32_bf16(const float* __restrict__ in, bf16* __restrict__ out, int n) {
    int i = (blockIdx.x * blockDim.x + threadIdx.x) * 4;
    int stride = gridDim.x * blockDim.x * 4;
    for (; i < n; i += stride) {
        float4 v = *(const float4*)(in + i);
        bf16x4 o;
        o[0] = (bf16)v.x; o[1] = (bf16)v.y; o[2] = (bf16)v.z; o[3] = (bf16)v.w;
        *(bf16x4*)(out + i) = o;
    }
}

// ---------------- transpose + convert: in [K][N] f32 -> out [N][K] bf16 ----------------
__global__ void transpose_f32_bf16(const float* __restrict__ in, bf16* __restrict__ out,
                                   int K, int N) {
    __shared__ bf16 tile[64][65];
    int n0 = blockIdx.x * 64, k0 = blockIdx.y * 64;
    int tc = threadIdx.x & 63, tr = threadIdx.x >> 6;
    #pragma unroll
    for (int p = 0; p < 16; ++p) {
        int k = tr + p * 4;
        tile[k][tc] = (bf16)in[(size_t)(k0 + k) * N + n0 + tc];
    }
    __syncthreads();
    #pragma unroll
    for (int p = 0; p < 16; ++p) {
        int n = tr + p * 4;
        out[(size_t)(n0 + n) * K + k0 + tc] = tile[tc][n];
    }
}

// ---------------- GEMM: C[M][N] = A[M][K] @ Bt[N][K]^T + bias ----------------
// 512 threads, BM=256 BN=128 BK=64, dbuf LDS + counted vmcnt(6) + raw s_barrier.
// LDS linear for global_load_lds; global SOURCE granule pre-swizzled j=(lane&7)^(lane>>3),
// fragment reads XOR granule with (l15&7) -> balanced bank use (T2-equivalent).
// MODE 0: per-block scatter to q / k / v^T ([B*H][D][T]) bf16; q pre-scaled by QSCALE.
// MODE 1: write f32 out [M][N].
template<int MODE>
__global__ __launch_bounds__(512, 2) void gemm8(
    const bf16* __restrict__ A, const bf16* __restrict__ Bt,
    const float* __restrict__ bias,
    void* __restrict__ out0, void* __restrict__ out1, void* __restrict__ out2,
    int M, int N, int K)
{
    constexpr int BM = 256, BN = 128, BK = 64;
    __shared__ bf16 As[2][BM * BK];   // 2 x 32 KB
    __shared__ bf16 Bs[2][BN * BK];   // 2 x 16 KB

    const int bx = blockIdx.x, by = blockIdx.y;
    const int tid = threadIdx.x;
    const int lane = tid & 63, w = tid >> 6;
    const int l15 = lane & 15, l4 = lane >> 4;
    const int wm = w >> 1, wn = w & 1;   // 4M x 2N waves; per-wave 64x64 C

    const bf16* Ab = A + (size_t)(by * BM) * K;
    const bf16* Bb = Bt + (size_t)(bx * BN) * K;

    // staging lane geometry: row-within-8 = lane>>3 (== local_row & 7), swizzled granule
    const int srow = lane >> 3;
    const int scol = ((lane & 7) ^ srow) * 8;

    // bias (4 cols per thread) — loaded before staging; extra vmcnt entries are benign
    float bv[4];
    #pragma unroll
    for (int n = 0; n < 4; ++n)
        bv[n] = bias[bx * BN + wn * 64 + n * 16 + l15];

    f32x4 acc[4][4] = {};

    auto stage = [&](int par, int t) {
        int k0 = t * BK;
        #pragma unroll
        for (int i = 0; i < 4; ++i) {
            int r = i * 64 + w * 8 + srow;
            async_copy16(Ab + (size_t)r * K + k0 + scol, &As[par][i * 4096 + w * 512]);
        }
        #pragma unroll
        for (int i = 0; i < 2; ++i) {
            int r = i * 64 + w * 8 + srow;
            async_copy16(Bb + (size_t)r * K + k0 + scol, &Bs[par][i * 4096 + w * 512]);
        }
    };

    stage(0, 0);
    const int NTK = K / BK;   // 16
    const int sx = l15 & 7;

    for (int t = 0; t < NTK; ++t) {
        int par = t & 1;
        if (t + 1 < NTK) {
            stage(par ^ 1, t + 1);
            asm volatile("s_waitcnt vmcnt(6)" ::: "memory");   // tile t resident; t+1 in flight
        } else {
            asm volatile("s_waitcnt vmcnt(0)" ::: "memory");
        }
        __builtin_amdgcn_sched_barrier(0);
        __builtin_amdgcn_s_barrier();
        __builtin_amdgcn_sched_barrier(0);

        bf16x8 afr[4][2], bfr[4][2];
        #pragma unroll
        for (int n = 0; n < 4; ++n)
            #pragma unroll
            for (int kk = 0; kk < 2; ++kk)
                bfr[n][kk] = *(const bf16x8*)(&Bs[par][(wn * 64 + n * 16 + l15) * 64 + ((kk * 4 + l4) ^ sx) * 8]);
        #pragma unroll
        for (int m = 0; m < 4; ++m)
            #pragma unroll
            for (int kk = 0; kk < 2; ++kk)
                afr[m][kk] = *(const bf16x8*)(&As[par][(wm * 64 + m * 16 + l15) * 64 + ((kk * 4 + l4) ^ sx) * 8]);

        __builtin_amdgcn_s_setprio(1);
        #pragma unroll
        for (int kk = 0; kk < 2; ++kk)
            #pragma unroll
            for (int m = 0; m < 4; ++m)
                #pragma unroll
                for (int n = 0; n < 4; ++n)
                    acc[m][n] = __builtin_amdgcn_mfma_f32_16x16x32_bf16(afr[m][kk], bfr[n][kk], acc[m][n], 0, 0, 0);
        __builtin_amdgcn_s_setprio(0);
        __builtin_amdgcn_sched_barrier(0);
        __builtin_amdgcn_s_barrier();
    }

    if constexpr (MODE == 0) {
        int which = bx >> 3;     // 0=q 1=k 2=v (block is uniform)
        int b = by >> 3;
        #pragma unroll
        for (int n = 0; n < 4; ++n) {
            int col = bx * 128 + wn * 64 + n * 16 + l15;
            int c = col & 1023;
            int h = c >> 6, d = c & 63;
            size_t bh = (size_t)(b * HH + h);
            #pragma unroll
            for (int m = 0; m < 4; ++m) {
                int row = by * 256 + wm * 64 + m * 16 + l4 * 4;
                int t0 = row & 2047;
                if (which == 2) {
                    bf16x4 pk;
                    #pragma unroll
                    for (int i = 0; i < 4; ++i) pk[i] = (bf16)(acc[m][n][i] + bv[n]);
                    *(bf16x4*)((bf16*)out2 + (bh * DD + d) * TT + t0) = pk;
                } else {
                    bf16* dst = (bf16*)(which == 0 ? out0 : out1);
                    float sc = (which == 0) ? QSCALE : 1.f;
                    #pragma unroll
                    for (int i = 0; i < 4; ++i)
                        dst[(bh * TT + t0 + i) * DD + d] = (bf16)((acc[m][n][i] + bv[n]) * sc);
                }
            }
        }
    } else {
        #pragma unroll
        for (int m = 0; m < 4; ++m) {
            #pragma unroll
            for (int n = 0; n < 4; ++n) {
                int row = by * 256 + wm * 64 + m * 16 + l4 * 4;
                int col = bx * 128 + wn * 64 + n * 16 + l15;
                #pragma unroll
                for (int i = 0; i < 4; ++i)
                    ((float*)out0)[(size_t)(row + i) * N + col] = acc[m][n][i] + bv[n];
            }
        }
    }
}

// ---------------- causal flash attention (swapped-QK, dbuf, defer-max, in-reg P) ----------------
__global__ __launch_bounds__(256, 3) void attn_kernel(
    const bf16* __restrict__ Q, const bf16* __restrict__ Kb, const bf16* __restrict__ Vt,
    bf16* __restrict__ Y)
{
    constexpr int PD = 72;
    __shared__ bf16 Ks[2][64 * PD];   // [key][d]
    __shared__ bf16 Vs[2][64 * PD];   // [d][key]

    int bh = blockIdx.x;           // 0..63
    int qt = 15 - (int)blockIdx.y; // heavy blocks dispatch first
    int b = bh >> 4, h = bh & 15;

    int tid = threadIdx.x;
    int lane = tid & 63, w = tid >> 6;
    int l15 = lane & 15, l4 = lane >> 4;

    const bf16* Qg = Q  + (size_t)bh * TT * DD;
    const bf16* Kg = Kb + (size_t)bh * TT * DD;
    const bf16* Vg = Vt + (size_t)bh * DD * TT;

    int q0 = qt * 128 + w * 32;    // wave's first q row

    bf16x8 qf[2][2];
    #pragma unroll
    for (int m = 0; m < 2; ++m)
        #pragma unroll
        for (int kk = 0; kk < 2; ++kk)
            qf[m][kk] = *(const bf16x8*)(Qg + (size_t)(q0 + m * 16 + l15) * DD + kk * 32 + l4 * 8);

    f32x4 o[2][4] = {};                 // o[mq][n]: q = q0+mq*16+l4*4+i, d = n*16+l15
    float mst[2] = {-1e30f, -1e30f};    // per q-row (ms, l15)
    float lst[2] = {0.f, 0.f};

    int NT = 2 * qt + 2;
    int sr = tid >> 3, sc = (tid & 7) * 8;

    bf16x8 kr0 = *(const bf16x8*)(Kg + (size_t)sr * DD + sc);
    bf16x8 kr1 = *(const bf16x8*)(Kg + (size_t)(sr + 32) * DD + sc);
    bf16x8 vr0 = *(const bf16x8*)(Vg + (size_t)sr * TT + sc);
    bf16x8 vr1 = *(const bf16x8*)(Vg + (size_t)(sr + 32) * TT + sc);

    for (int kt = 0; kt < NT; ++kt) {
        int buf = kt & 1;
        *(bf16x8*)(&Ks[buf][(size_t)sr * PD + sc])        = kr0;
        *(bf16x8*)(&Ks[buf][(size_t)(sr + 32) * PD + sc]) = kr1;
        *(bf16x8*)(&Vs[buf][(size_t)sr * PD + sc])        = vr0;
        *(bf16x8*)(&Vs[buf][(size_t)(sr + 32) * PD + sc]) = vr1;
        if (kt + 1 < NT) {
            const bf16* kp = Kg + (size_t)((kt + 1) * 64 + sr) * DD + sc;
            kr0 = *(const bf16x8*)(kp);
            kr1 = *(const bf16x8*)(kp + 32 * DD);
            const bf16* vp = Vg + (size_t)sr * TT + (kt + 1) * 64 + sc;
            vr0 = *(const bf16x8*)(vp);
            vr1 = *(const bf16x8*)(vp + (size_t)32 * TT);
        }
        __syncthreads();

        if (kt * 64 <= q0 + 31) {
            int ktb = kt * 64;
            f32x4 s[2][4] = {};
            #pragma unroll
            for (int kk = 0; kk < 2; ++kk) {
                bf16x8 kf[4];
                #pragma unroll
                for (int n = 0; n < 4; ++n)
                    kf[n] = *(const bf16x8*)(&Ks[buf][(n * 16 + l15) * PD + kk * 32 + l4 * 8]);
                #pragma unroll
                for (int ms = 0; ms < 2; ++ms)
                    #pragma unroll
                    for (int n = 0; n < 4; ++n)
                        s[ms][n] = __builtin_amdgcn_mfma_f32_16x16x32_bf16(kf[n], qf[ms][kk], s[ms][n], 0, 0, 0);
            }

            bf16x8 paf[2][2];
            #pragma unroll
            for (int ms = 0; ms < 2; ++ms) {
                int qr = q0 + ms * 16 + l15;
                if (ktb + 63 > q0 + ms * 16) {
                    #pragma unroll
                    for (int n = 0; n < 4; ++n) {
                        int keyb = ktb + n * 16 + l4 * 4;
                        #pragma unroll
                        for (int i = 0; i < 4; ++i)
                            if (keyb + i > qr) s[ms][n][i] = -1e30f;
                    }
                }
                float mx0 = fmaxf(fmaxf(s[ms][0][0], s[ms][0][1]), fmaxf(s[ms][0][2], s[ms][0][3]));
                float mx1 = fmaxf(fmaxf(s[ms][1][0], s[ms][1][1]), fmaxf(s[ms][1][2], s[ms][1][3]));
                float mx2 = fmaxf(fmaxf(s[ms][2][0], s[ms][2][1]), fmaxf(s[ms][2][2], s[ms][2][3]));
                float mx3 = fmaxf(fmaxf(s[ms][3][0], s[ms][3][1]), fmaxf(s[ms][3][2], s[ms][3][3]));
                float mx = fmaxf(fmaxf(mx0, mx1), fmaxf(mx2, mx3));
                mx = fmaxf(mx, __shfl_xor(mx, 16));
                mx = fmaxf(mx, __shfl_xor(mx, 32));

                if (__any(mx > mst[ms] + 11.5f)) {
                    float mnew = fmaxf(mst[ms], mx);
                    float sc2 = exp2f(mst[ms] - mnew);
                    mst[ms] = mnew;
                    lst[ms] *= sc2;
                    float scl[4];
                    #pragma unroll
                    for (int i = 0; i < 4; ++i) scl[i] = __shfl(sc2, l4 * 4 + i);
                    #pragma unroll
                    for (int n = 0; n < 4; ++n)
                        #pragma unroll
                        for (int i = 0; i < 4; ++i) o[ms][n][i] *= scl[i];
                }

                uint pk_[4][2];
                float rs = 0.f;
                #pragma unroll
                for (int n = 0; n < 4; ++n) {
                    float p0 = exp2f(s[ms][n][0] - mst[ms]);
                    float p1 = exp2f(s[ms][n][1] - mst[ms]);
                    float p2 = exp2f(s[ms][n][2] - mst[ms]);
                    float p3 = exp2f(s[ms][n][3] - mst[ms]);
                    rs += (p0 + p1) + (p2 + p3);
                    asm("v_cvt_pk_bf16_f32 %0, %1, %2" : "=v"(pk_[n][0]) : "v"(p0), "v"(p1));
                    asm("v_cvt_pk_bf16_f32 %0, %1, %2" : "=v"(pk_[n][1]) : "v"(p2), "v"(p3));
                }
                rs += __shfl_xor(rs, 16);
                rs += __shfl_xor(rs, 32);
                lst[ms] += rs;

                asm("v_permlane32_swap_b32 %0, %1" : "+v"(pk_[0][0]), "+v"(pk_[1][0]));
                asm("v_permlane32_swap_b32 %0, %1" : "+v"(pk_[0][1]), "+v"(pk_[1][1]));
                asm("v_permlane32_swap_b32 %0, %1" : "+v"(pk_[2][0]), "+v"(pk_[3][0]));
                asm("v_permlane32_swap_b32 %0, %1" : "+v"(pk_[2][1]), "+v"(pk_[3][1]));
                asm("v_permlane16_swap_b32 %0, %1" : "+v"(pk_[0][0]), "+v"(pk_[1][0]));
                asm("v_permlane16_swap_b32 %0, %1" : "+v"(pk_[0][1]), "+v"(pk_[1][1]));
                asm("v_permlane16_swap_b32 %0, %1" : "+v"(pk_[2][0]), "+v"(pk_[3][0]));
                asm("v_permlane16_swap_b32 %0, %1" : "+v"(pk_[2][1]), "+v"(pk_[3][1]));
                uint4 u0 = {pk_[0][0], pk_[0][1], pk_[1][0], pk_[1][1]};
                uint4 u1 = {pk_[2][0], pk_[2][1], pk_[3][0], pk_[3][1]};
                paf[ms][0] = __builtin_bit_cast(bf16x8, u0);
                paf[ms][1] = __builtin_bit_cast(bf16x8, u1);
            }

            #pragma unroll
            for (int kk = 0; kk < 2; ++kk) {
                bf16x8 vf[4];
                #pragma unroll
                for (int n = 0; n < 4; ++n)
                    vf[n] = *(const bf16x8*)(&Vs[buf][(n * 16 + l15) * PD + kk * 32 + l4 * 8]);
                #pragma unroll
                for (int mq = 0; mq < 2; ++mq)
                    #pragma unroll
                    for (int n = 0; n < 4; ++n)
                        o[mq][n] = __builtin_amdgcn_mfma_f32_16x16x32_bf16(paf[mq][kk], vf[n], o[mq][n], 0, 0, 0);
            }
        }
    }

    #pragma unroll
    for (int mq = 0; mq < 2; ++mq) {
        float inv[4];
        #pragma unroll
        for (int i = 0; i < 4; ++i) inv[i] = 1.f / __shfl(lst[mq], l4 * 4 + i);
        #pragma unroll
        for (int i = 0; i < 4; ++i) {
            int t = q0 + mq * 16 + l4 * 4 + i;
            #pragma unroll
            for (int n = 0; n < 4; ++n) {
                int d = n * 16 + l15;
                Y[((size_t)(b * TT + t)) * CC + h * DD + d] = (bf16)(o[mq][n][i] * inv[i]);
            }
        }
    }
}

extern "C" void kernel_launch(void* const* d_in, const int* in_sizes, int n_in,
                              void* d_out, int out_size, void* d_ws, size_t ws_size,
                              hipStream_t stream) {
    const float* x      = (const float*)d_in[0];
    const float* w_attn = (const float*)d_in[1];
    const float* b_attn = (const float*)d_in[2];
    const float* w_proj = (const float*)d_in[3];
    const float* b_proj = (const float*)d_in[4];
    float* out = (float*)d_out;

    bf16* xb  = (bf16*)d_ws;                        // [8192][1024]
    bf16* waT = xb  + (size_t)MM * CC;              // [3072][1024]
    bf16* wpT = waT + (size_t)3 * CC * CC;          // [1024][1024]
    bf16* qb  = wpT + (size_t)CC * CC;              // [B*H][T][D]
    bf16* kb  = qb  + (size_t)MM * CC;              // [B*H][T][D]
    bf16* vt  = kb  + (size_t)MM * CC;              // [B*H][D][T] (written directly by gemm8<0>)
    bf16* yb  = vt  + (size_t)MM * CC;              // [8192][1024] attention output

    conv_f32_bf16<<<2048, 256, 0, stream>>>(x, xb, MM * CC);
    transpose_f32_bf16<<<dim3(3 * CC / 64, CC / 64), 256, 0, stream>>>(w_attn, waT, CC, 3 * CC);
    transpose_f32_bf16<<<dim3(CC / 64, CC / 64), 256, 0, stream>>>(w_proj, wpT, CC, CC);

    gemm8<0><<<dim3(3 * CC / 128, MM / 256), 512, 0, stream>>>(
        xb, waT, b_attn, qb, kb, vt, MM, 3 * CC, CC);

    attn_kernel<<<dim3(BB * HH, TT / 128), 256, 0, stream>>>(qb, kb, vt, yb);

    gemm8<1><<<dim3(CC / 128, MM / 256), 512, 0, stream>>>(
        yb, wpT, b_proj, out, nullptr, nullptr, MM, CC, CC);
}

// Round 6
// 183.589 us; speedup vs baseline: 1.6212x; 1.0490x over previous
//
#include <hip/hip_runtime.h>

typedef __bf16 bf16;
typedef __bf16 bf16x8 __attribute__((ext_vector_type(8)));
typedef __bf16 bf16x4 __attribute__((ext_vector_type(4)));
typedef float f32x4 __attribute__((ext_vector_type(4)));
typedef unsigned int uint;

// Problem constants
#define BB 4
#define TT 2048
#define CC 1024
#define HH 16
#define DD 64
#define MM (BB*TT)   // 8192

// softmax scale folded into q: 1/sqrt(64) * log2(e)  (we use exp2 in the kernel)
#define QSCALE (0.125f * 1.4426950408889634f)

__device__ __forceinline__ void async_copy16(const bf16* g, bf16* l) {
    __builtin_amdgcn_global_load_lds((const __attribute__((address_space(1))) void*)g,
                                     (__attribute__((address_space(3))) void*)l, 16, 0, 0);
}

// single-instruction 2^x (libm exp2f without -ffast-math expands to ~12 insts)
__device__ __forceinline__ float ex2(float x) {
#if __has_builtin(__builtin_amdgcn_exp2f)
    return __builtin_amdgcn_exp2f(x);
#else
    float r; asm("v_exp_f32 %0, %1" : "=v"(r) : "v"(x)); return r;
#endif
}

// ---------------- convert f32 -> bf16 ----------------
__global__ void conv_f32_bf16(const float* __restrict__ in, bf16* __restrict__ out, int n) {
    int i = (blockIdx.x * blockDim.x + threadIdx.x) * 4;
    int stride = gridDim.x * blockDim.x * 4;
    for (; i < n; i += stride) {
        float4 v = *(const float4*)(in + i);
        bf16x4 o;
        o[0] = (bf16)v.x; o[1] = (bf16)v.y; o[2] = (bf16)v.z; o[3] = (bf16)v.w;
        *(bf16x4*)(out + i) = o;
    }
}

// ---------------- transpose + convert: in [K][N] f32 -> out [N][K] bf16 ----------------
__global__ void transpose_f32_bf16(const float* __restrict__ in, bf16* __restrict__ out,
                                   int K, int N) {
    __shared__ bf16 tile[64][65];
    int n0 = blockIdx.x * 64, k0 = blockIdx.y * 64;
    int tc = threadIdx.x & 63, tr = threadIdx.x >> 6;
    #pragma unroll
    for (int p = 0; p < 16; ++p) {
        int k = tr + p * 4;
        tile[k][tc] = (bf16)in[(size_t)(k0 + k) * N + n0 + tc];
    }
    __syncthreads();
    #pragma unroll
    for (int p = 0; p < 16; ++p) {
        int n = tr + p * 4;
        out[(size_t)(n0 + n) * K + k0 + tc] = tile[tc][n];
    }
}

// ---------------- GEMM: C[M][N] = A[M][K] @ Bt[N][K]^T + bias ----------------
// 512 threads, BM=256 BN=128 BK=64, dbuf LDS + counted vmcnt(6) + raw s_barrier.
template<int MODE>
__global__ __launch_bounds__(512, 2) void gemm8(
    const bf16* __restrict__ A, const bf16* __restrict__ Bt,
    const float* __restrict__ bias,
    void* __restrict__ out0, void* __restrict__ out1, void* __restrict__ out2,
    int M, int N, int K)
{
    constexpr int BM = 256, BN = 128, BK = 64;
    __shared__ bf16 As[2][BM * BK];   // 2 x 32 KB
    __shared__ bf16 Bs[2][BN * BK];   // 2 x 16 KB

    const int bx = blockIdx.x, by = blockIdx.y;
    const int tid = threadIdx.x;
    const int lane = tid & 63, w = tid >> 6;
    const int l15 = lane & 15, l4 = lane >> 4;
    const int wm = w >> 1, wn = w & 1;   // 4M x 2N waves; per-wave 64x64 C

    const bf16* Ab = A + (size_t)(by * BM) * K;
    const bf16* Bb = Bt + (size_t)(bx * BN) * K;

    const int srow = lane >> 3;
    const int scol = ((lane & 7) ^ srow) * 8;

    float bv[4];
    #pragma unroll
    for (int n = 0; n < 4; ++n)
        bv[n] = bias[bx * BN + wn * 64 + n * 16 + l15];

    f32x4 acc[4][4] = {};

    auto stage = [&](int par, int t) {
        int k0 = t * BK;
        #pragma unroll
        for (int i = 0; i < 4; ++i) {
            int r = i * 64 + w * 8 + srow;
            async_copy16(Ab + (size_t)r * K + k0 + scol, &As[par][i * 4096 + w * 512]);
        }
        #pragma unroll
        for (int i = 0; i < 2; ++i) {
            int r = i * 64 + w * 8 + srow;
            async_copy16(Bb + (size_t)r * K + k0 + scol, &Bs[par][i * 4096 + w * 512]);
        }
    };

    stage(0, 0);
    const int NTK = K / BK;   // 16
    const int sx = l15 & 7;

    for (int t = 0; t < NTK; ++t) {
        int par = t & 1;
        if (t + 1 < NTK) {
            stage(par ^ 1, t + 1);
            asm volatile("s_waitcnt vmcnt(6)" ::: "memory");
        } else {
            asm volatile("s_waitcnt vmcnt(0)" ::: "memory");
        }
        __builtin_amdgcn_sched_barrier(0);
        __builtin_amdgcn_s_barrier();
        __builtin_amdgcn_sched_barrier(0);

        bf16x8 afr[4][2], bfr[4][2];
        #pragma unroll
        for (int n = 0; n < 4; ++n)
            #pragma unroll
            for (int kk = 0; kk < 2; ++kk)
                bfr[n][kk] = *(const bf16x8*)(&Bs[par][(wn * 64 + n * 16 + l15) * 64 + ((kk * 4 + l4) ^ sx) * 8]);
        #pragma unroll
        for (int m = 0; m < 4; ++m)
            #pragma unroll
            for (int kk = 0; kk < 2; ++kk)
                afr[m][kk] = *(const bf16x8*)(&As[par][(wm * 64 + m * 16 + l15) * 64 + ((kk * 4 + l4) ^ sx) * 8]);

        __builtin_amdgcn_s_setprio(1);
        #pragma unroll
        for (int kk = 0; kk < 2; ++kk)
            #pragma unroll
            for (int m = 0; m < 4; ++m)
                #pragma unroll
                for (int n = 0; n < 4; ++n)
                    acc[m][n] = __builtin_amdgcn_mfma_f32_16x16x32_bf16(afr[m][kk], bfr[n][kk], acc[m][n], 0, 0, 0);
        __builtin_amdgcn_s_setprio(0);
        __builtin_amdgcn_sched_barrier(0);
        __builtin_amdgcn_s_barrier();
    }

    if constexpr (MODE == 0) {
        int which = bx >> 3;     // 0=q 1=k 2=v (block is uniform)
        int b = by >> 3;
        #pragma unroll
        for (int n = 0; n < 4; ++n) {
            int col = bx * 128 + wn * 64 + n * 16 + l15;
            int c = col & 1023;
            int h = c >> 6, d = c & 63;
            size_t bh = (size_t)(b * HH + h);
            #pragma unroll
            for (int m = 0; m < 4; ++m) {
                int row = by * 256 + wm * 64 + m * 16 + l4 * 4;
                int t0 = row & 2047;
                if (which == 2) {
                    bf16x4 pk;
                    #pragma unroll
                    for (int i = 0; i < 4; ++i) pk[i] = (bf16)(acc[m][n][i] + bv[n]);
                    *(bf16x4*)((bf16*)out2 + (bh * DD + d) * TT + t0) = pk;
                } else {
                    bf16* dst = (bf16*)(which == 0 ? out0 : out1);
                    float sc = (which == 0) ? QSCALE : 1.f;
                    #pragma unroll
                    for (int i = 0; i < 4; ++i)
                        dst[(bh * TT + t0 + i) * DD + d] = (bf16)((acc[m][n][i] + bv[n]) * sc);
                }
            }
        }
    } else {
        #pragma unroll
        for (int m = 0; m < 4; ++m) {
            #pragma unroll
            for (int n = 0; n < 4; ++n) {
                int row = by * 256 + wm * 64 + m * 16 + l4 * 4;
                int col = bx * 128 + wn * 64 + n * 16 + l15;
                #pragma unroll
                for (int i = 0; i < 4; ++i)
                    ((float*)out0)[(size_t)(row + i) * N + col] = acc[m][n][i] + bv[n];
            }
        }
    }
}

// ---------------- causal flash attention (swapped-QK, dbuf, defer-max, in-reg P) ----------------
// Balanced pairing: grid y = 0..7; block processes q-tile (15-y) then (y):
// uniform 34 tiles per block, 512 equal blocks. NT always even, so the dbuf
// parity across parts never collides (part A ends on buf1, part B starts buf0).
__global__ __launch_bounds__(256, 2) void attn_kernel(
    const bf16* __restrict__ Q, const bf16* __restrict__ Kb, const bf16* __restrict__ Vt,
    bf16* __restrict__ Y)
{
    constexpr int PD = 72;
    __shared__ bf16 Ks[2][64 * PD];   // [key][d]
    __shared__ bf16 Vs[2][64 * PD];   // [d][key]

    int bh = blockIdx.x;           // 0..63
    int b = bh >> 4, h = bh & 15;

    int tid = threadIdx.x;
    int lane = tid & 63, w = tid >> 6;
    int l15 = lane & 15, l4 = lane >> 4;

    const bf16* Qg = Q  + (size_t)bh * TT * DD;
    const bf16* Kg = Kb + (size_t)bh * TT * DD;
    const bf16* Vg = Vt + (size_t)bh * DD * TT;

    int sr = tid >> 3, sc = (tid & 7) * 8;

    #pragma unroll
    for (int part = 0; part < 2; ++part) {
        int qt = part == 0 ? (15 - (int)blockIdx.y) : (int)blockIdx.y;
        int q0 = qt * 128 + w * 32;    // wave's first q row

        bf16x8 qf[2][2];
        #pragma unroll
        for (int m = 0; m < 2; ++m)
            #pragma unroll
            for (int kk = 0; kk < 2; ++kk)
                qf[m][kk] = *(const bf16x8*)(Qg + (size_t)(q0 + m * 16 + l15) * DD + kk * 32 + l4 * 8);

        f32x4 o[2][4] = {};                 // o[mq][n]: q = q0+mq*16+l4*4+i, d = n*16+l15
        float mst[2] = {-1e30f, -1e30f};    // per q-row (ms, l15)
        float lst[2] = {0.f, 0.f};

        int NT = 2 * qt + 2;

        // incremental staging pointers
        const bf16* kp = Kg + (size_t)sr * DD + sc;
        const bf16* vp = Vg + (size_t)sr * TT + sc;
        bf16x8 kr0 = *(const bf16x8*)(kp);
        bf16x8 kr1 = *(const bf16x8*)(kp + 32 * DD);
        bf16x8 vr0 = *(const bf16x8*)(vp);
        bf16x8 vr1 = *(const bf16x8*)(vp + (size_t)32 * TT);
        kp += 64 * DD; vp += 64;

        for (int kt = 0; kt < NT; ++kt) {
            int buf = kt & 1;
            *(bf16x8*)(&Ks[buf][(size_t)sr * PD + sc])        = kr0;
            *(bf16x8*)(&Ks[buf][(size_t)(sr + 32) * PD + sc]) = kr1;
            *(bf16x8*)(&Vs[buf][(size_t)sr * PD + sc])        = vr0;
            *(bf16x8*)(&Vs[buf][(size_t)(sr + 32) * PD + sc]) = vr1;
            if (kt + 1 < NT) {
                kr0 = *(const bf16x8*)(kp);
                kr1 = *(const bf16x8*)(kp + 32 * DD);
                vr0 = *(const bf16x8*)(vp);
                vr1 = *(const bf16x8*)(vp + (size_t)32 * TT);
                kp += 64 * DD; vp += 64;
            }
            __syncthreads();

            if (kt * 64 <= q0 + 31) {
                int ktb = kt * 64;
                f32x4 s[2][4] = {};
                #pragma unroll
                for (int kk = 0; kk < 2; ++kk) {
                    bf16x8 kf[4];
                    #pragma unroll
                    for (int n = 0; n < 4; ++n)
                        kf[n] = *(const bf16x8*)(&Ks[buf][(n * 16 + l15) * PD + kk * 32 + l4 * 8]);
                    #pragma unroll
                    for (int ms = 0; ms < 2; ++ms)
                        #pragma unroll
                        for (int n = 0; n < 4; ++n)
                            s[ms][n] = __builtin_amdgcn_mfma_f32_16x16x32_bf16(kf[n], qf[ms][kk], s[ms][n], 0, 0, 0);
                }

                bf16x8 paf[2][2];
                #pragma unroll
                for (int ms = 0; ms < 2; ++ms) {
                    int qr = q0 + ms * 16 + l15;
                    if (ktb + 63 > q0 + ms * 16) {
                        #pragma unroll
                        for (int n = 0; n < 4; ++n) {
                            int keyb = ktb + n * 16 + l4 * 4;
                            #pragma unroll
                            for (int i = 0; i < 4; ++i)
                                if (keyb + i > qr) s[ms][n][i] = -1e30f;
                        }
                    }
                    float mx0 = fmaxf(fmaxf(s[ms][0][0], s[ms][0][1]), fmaxf(s[ms][0][2], s[ms][0][3]));
                    float mx1 = fmaxf(fmaxf(s[ms][1][0], s[ms][1][1]), fmaxf(s[ms][1][2], s[ms][1][3]));
                    float mx2 = fmaxf(fmaxf(s[ms][2][0], s[ms][2][1]), fmaxf(s[ms][2][2], s[ms][2][3]));
                    float mx3 = fmaxf(fmaxf(s[ms][3][0], s[ms][3][1]), fmaxf(s[ms][3][2], s[ms][3][3]));
                    float mx = fmaxf(fmaxf(mx0, mx1), fmaxf(mx2, mx3));
                    mx = fmaxf(mx, __shfl_xor(mx, 16));
                    mx = fmaxf(mx, __shfl_xor(mx, 32));

                    if (__any(mx > mst[ms] + 11.5f)) {
                        float mnew = fmaxf(mst[ms], mx);
                        float sc2 = ex2(mst[ms] - mnew);
                        mst[ms] = mnew;
                        lst[ms] *= sc2;
                        float scl[4];
                        #pragma unroll
                        for (int i = 0; i < 4; ++i) scl[i] = __shfl(sc2, l4 * 4 + i);
                        #pragma unroll
                        for (int n = 0; n < 4; ++n)
                            #pragma unroll
                            for (int i = 0; i < 4; ++i) o[ms][n][i] *= scl[i];
                    }

                    uint pk_[4][2];
                    float rs = 0.f;
                    #pragma unroll
                    for (int n = 0; n < 4; ++n) {
                        float p0 = ex2(s[ms][n][0] - mst[ms]);
                        float p1 = ex2(s[ms][n][1] - mst[ms]);
                        float p2 = ex2(s[ms][n][2] - mst[ms]);
                        float p3 = ex2(s[ms][n][3] - mst[ms]);
                        rs += (p0 + p1) + (p2 + p3);
                        asm("v_cvt_pk_bf16_f32 %0, %1, %2" : "=v"(pk_[n][0]) : "v"(p0), "v"(p1));
                        asm("v_cvt_pk_bf16_f32 %0, %1, %2" : "=v"(pk_[n][1]) : "v"(p2), "v"(p3));
                    }
                    rs += __shfl_xor(rs, 16);
                    rs += __shfl_xor(rs, 32);
                    lst[ms] += rs;

                    asm("v_permlane32_swap_b32 %0, %1" : "+v"(pk_[0][0]), "+v"(pk_[1][0]));
                    asm("v_permlane32_swap_b32 %0, %1" : "+v"(pk_[0][1]), "+v"(pk_[1][1]));
                    asm("v_permlane32_swap_b32 %0, %1" : "+v"(pk_[2][0]), "+v"(pk_[3][0]));
                    asm("v_permlane32_swap_b32 %0, %1" : "+v"(pk_[2][1]), "+v"(pk_[3][1]));
                    asm("v_permlane16_swap_b32 %0, %1" : "+v"(pk_[0][0]), "+v"(pk_[1][0]));
                    asm("v_permlane16_swap_b32 %0, %1" : "+v"(pk_[0][1]), "+v"(pk_[1][1]));
                    asm("v_permlane16_swap_b32 %0, %1" : "+v"(pk_[2][0]), "+v"(pk_[3][0]));
                    asm("v_permlane16_swap_b32 %0, %1" : "+v"(pk_[2][1]), "+v"(pk_[3][1]));
                    uint4 u0 = {pk_[0][0], pk_[0][1], pk_[1][0], pk_[1][1]};
                    uint4 u1 = {pk_[2][0], pk_[2][1], pk_[3][0], pk_[3][1]};
                    paf[ms][0] = __builtin_bit_cast(bf16x8, u0);
                    paf[ms][1] = __builtin_bit_cast(bf16x8, u1);
                }

                #pragma unroll
                for (int kk = 0; kk < 2; ++kk) {
                    bf16x8 vf[4];
                    #pragma unroll
                    for (int n = 0; n < 4; ++n)
                        vf[n] = *(const bf16x8*)(&Vs[buf][(n * 16 + l15) * PD + kk * 32 + l4 * 8]);
                    #pragma unroll
                    for (int mq = 0; mq < 2; ++mq)
                        #pragma unroll
                        for (int n = 0; n < 4; ++n)
                            o[mq][n] = __builtin_amdgcn_mfma_f32_16x16x32_bf16(paf[mq][kk], vf[n], o[mq][n], 0, 0, 0);
                }
            }
        }

        #pragma unroll
        for (int mq = 0; mq < 2; ++mq) {
            float inv[4];
            #pragma unroll
            for (int i = 0; i < 4; ++i) inv[i] = 1.f / __shfl(lst[mq], l4 * 4 + i);
            #pragma unroll
            for (int i = 0; i < 4; ++i) {
                int t = q0 + mq * 16 + l4 * 4 + i;
                #pragma unroll
                for (int n = 0; n < 4; ++n) {
                    int d = n * 16 + l15;
                    Y[((size_t)(b * TT + t)) * CC + h * DD + d] = (bf16)(o[mq][n][i] * inv[i]);
                }
            }
        }
    }
}

extern "C" void kernel_launch(void* const* d_in, const int* in_sizes, int n_in,
                              void* d_out, int out_size, void* d_ws, size_t ws_size,
                              hipStream_t stream) {
    const float* x      = (const float*)d_in[0];
    const float* w_attn = (const float*)d_in[1];
    const float* b_attn = (const float*)d_in[2];
    const float* w_proj = (const float*)d_in[3];
    const float* b_proj = (const float*)d_in[4];
    float* out = (float*)d_out;

    bf16* xb  = (bf16*)d_ws;                        // [8192][1024]
    bf16* waT = xb  + (size_t)MM * CC;              // [3072][1024]
    bf16* wpT = waT + (size_t)3 * CC * CC;          // [1024][1024]
    bf16* qb  = wpT + (size_t)CC * CC;              // [B*H][T][D]
    bf16* kb  = qb  + (size_t)MM * CC;              // [B*H][T][D]
    bf16* vt  = kb  + (size_t)MM * CC;              // [B*H][D][T] (written directly by gemm8<0>)
    bf16* yb  = vt  + (size_t)MM * CC;              // [8192][1024] attention output

    conv_f32_bf16<<<2048, 256, 0, stream>>>(x, xb, MM * CC);
    transpose_f32_bf16<<<dim3(3 * CC / 64, CC / 64), 256, 0, stream>>>(w_attn, waT, CC, 3 * CC);
    transpose_f32_bf16<<<dim3(CC / 64, CC / 64), 256, 0, stream>>>(w_proj, wpT, CC, CC);

    gemm8<0><<<dim3(3 * CC / 128, MM / 256), 512, 0, stream>>>(
        xb, waT, b_attn, qb, kb, vt, MM, 3 * CC, CC);

    attn_kernel<<<dim3(BB * HH, 8), 256, 0, stream>>>(qb, kb, vt, yb);

    gemm8<1><<<dim3(CC / 128, MM / 256), 512, 0, stream>>>(
        yb, wpT, b_proj, out, nullptr, nullptr, MM, CC, CC);
}

// Round 7
// 182.516 us; speedup vs baseline: 1.6307x; 1.0059x over previous
//
#include <hip/hip_runtime.h>

typedef __bf16 bf16;
typedef __bf16 bf16x8 __attribute__((ext_vector_type(8)));
typedef __bf16 bf16x4 __attribute__((ext_vector_type(4)));
typedef float f32x4 __attribute__((ext_vector_type(4)));
typedef unsigned int uint;

// Problem constants
#define BB 4
#define TT 2048
#define CC 1024
#define HH 16
#define DD 64
#define MM (BB*TT)   // 8192

// softmax scale folded into q: 1/sqrt(64) * log2(e)  (we use exp2 in the kernel)
#define QSCALE (0.125f * 1.4426950408889634f)

__device__ __forceinline__ void async_copy16(const bf16* g, bf16* l) {
    __builtin_amdgcn_global_load_lds((const __attribute__((address_space(1))) void*)g,
                                     (__attribute__((address_space(3))) void*)l, 16, 0, 0);
}

// single-instruction 2^x (libm exp2f without -ffast-math expands to ~12 insts)
__device__ __forceinline__ float ex2(float x) {
#if __has_builtin(__builtin_amdgcn_exp2f)
    return __builtin_amdgcn_exp2f(x);
#else
    float r; asm("v_exp_f32 %0, %1" : "=v"(r) : "v"(x)); return r;
#endif
}

// ---------------- convert f32 -> bf16 ----------------
__global__ void conv_f32_bf16(const float* __restrict__ in, bf16* __restrict__ out, int n) {
    int i = (blockIdx.x * blockDim.x + threadIdx.x) * 4;
    int stride = gridDim.x * blockDim.x * 4;
    for (; i < n; i += stride) {
        float4 v = *(const float4*)(in + i);
        bf16x4 o;
        o[0] = (bf16)v.x; o[1] = (bf16)v.y; o[2] = (bf16)v.z; o[3] = (bf16)v.w;
        *(bf16x4*)(out + i) = o;
    }
}

// ---------------- transpose + convert: in [K][N] f32 -> out [N][K] bf16 ----------------
__global__ void transpose_f32_bf16(const float* __restrict__ in, bf16* __restrict__ out,
                                   int K, int N) {
    __shared__ bf16 tile[64][65];
    int n0 = blockIdx.x * 64, k0 = blockIdx.y * 64;
    int tc = threadIdx.x & 63, tr = threadIdx.x >> 6;
    #pragma unroll
    for (int p = 0; p < 16; ++p) {
        int k = tr + p * 4;
        tile[k][tc] = (bf16)in[(size_t)(k0 + k) * N + n0 + tc];
    }
    __syncthreads();
    #pragma unroll
    for (int p = 0; p < 16; ++p) {
        int n = tr + p * 4;
        out[(size_t)(n0 + n) * K + k0 + tc] = tile[tc][n];
    }
}

// ---------------- GEMM: C[M][N] = A[M][K] @ Bt[N][K]^T + bias ----------------
// 512 threads, BM=256 BN=128 BK=64. Triple-buffered LDS, 2 phases per K-tile
// (phase = kk half: 8 ds_read_b128 + 16 MFMA), counted vmcnt(10) at group start.
// Pipeline: group j reads tile Tj (buf j%3) and stages T_{j+2} into buf (j+2)%3
// (T_{j-1}'s reads ended a full group earlier -> no WAR). vmcnt(10) leaves
// T_{j+1}(6 loads) + T_{j+2}A(4) in flight, guarantees Tj landed.
// XCD-chunked block remap: blocks sharing an A-panel land on one XCD's L2.
template<int MODE>
__global__ __launch_bounds__(512, 2) void gemm8(
    const bf16* __restrict__ A, const bf16* __restrict__ Bt,
    const float* __restrict__ bias,
    void* __restrict__ out0, void* __restrict__ out1, void* __restrict__ out2,
    int M, int N, int K)
{
    constexpr int BM = 256, BN = 128, BK = 64, NTK = 16;
    __shared__ bf16 As[3][BM * BK];   // 3 x 32 KB
    __shared__ bf16 Bs[3][BN * BK];   // 3 x 16 KB

    // bijective XCD-chunked remap (nwg % 8 == 0 for both GEMMs: 768, 256)
    int nwg = gridDim.x * gridDim.y;
    int id  = blockIdx.y * gridDim.x + blockIdx.x;
    int sid = (id & 7) * (nwg >> 3) + (id >> 3);
    int bx = sid % gridDim.x, by = sid / gridDim.x;

    const int tid = threadIdx.x;
    const int lane = tid & 63, w = tid >> 6;
    const int l15 = lane & 15, l4 = lane >> 4;
    const int wm = w >> 1, wn = w & 1;   // 4M x 2N waves; per-wave 64x64 C

    const bf16* Ab = A + (size_t)(by * BM) * K;
    const bf16* Bb = Bt + (size_t)(bx * BN) * K;

    const int srow = lane >> 3;
    const int scol = ((lane & 7) ^ srow) * 8;
    const int sx = l15 & 7;

    float bv[4];
    #pragma unroll
    for (int n = 0; n < 4; ++n)
        bv[n] = bias[bx * BN + wn * 64 + n * 16 + l15];

    f32x4 acc[4][4] = {};

    auto stageA = [&](int sb, int t) {
        int k0 = t * BK;
        #pragma unroll
        for (int i = 0; i < 4; ++i) {
            int r = i * 64 + w * 8 + srow;
            async_copy16(Ab + (size_t)r * K + k0 + scol, &As[sb][i * 4096 + w * 512]);
        }
    };
    auto stageB = [&](int sb, int t) {
        int k0 = t * BK;
        #pragma unroll
        for (int i = 0; i < 2; ++i) {
            int r = i * 64 + w * 8 + srow;
            async_copy16(Bb + (size_t)r * K + k0 + scol, &Bs[sb][i * 4096 + w * 512]);
        }
    };

    // prologue: T0 -> buf0, T1 -> buf1 (6 loads each)
    stageA(0, 0); stageB(0, 0);
    stageA(1, 1); stageB(1, 1);

    int cur = 0, sb = 2;
    for (int j = 0; j < NTK; ++j) {
        // ---- phase 1 (kk = 0) ----
        if (j < NTK - 2) stageA(sb, j + 2);
        if (j < NTK - 2)      { asm volatile("s_waitcnt vmcnt(10)" ::: "memory"); }
        else if (j == NTK - 2){ asm volatile("s_waitcnt vmcnt(6)" ::: "memory"); }
        else                  { asm volatile("s_waitcnt vmcnt(0)" ::: "memory"); }
        __builtin_amdgcn_sched_barrier(0);
        __builtin_amdgcn_s_barrier();
        __builtin_amdgcn_sched_barrier(0);

        {
            bf16x8 a0[4], b0[4];
            #pragma unroll
            for (int n = 0; n < 4; ++n)
                b0[n] = *(const bf16x8*)(&Bs[cur][(wn * 64 + n * 16 + l15) * 64 + (l4 ^ sx) * 8]);
            #pragma unroll
            for (int m = 0; m < 4; ++m)
                a0[m] = *(const bf16x8*)(&As[cur][(wm * 64 + m * 16 + l15) * 64 + (l4 ^ sx) * 8]);
            __builtin_amdgcn_s_setprio(1);
            #pragma unroll
            for (int m = 0; m < 4; ++m)
                #pragma unroll
                for (int n = 0; n < 4; ++n)
                    acc[m][n] = __builtin_amdgcn_mfma_f32_16x16x32_bf16(a0[m], b0[n], acc[m][n], 0, 0, 0);
            __builtin_amdgcn_s_setprio(0);
        }
        __builtin_amdgcn_sched_barrier(0);
        __builtin_amdgcn_s_barrier();

        // ---- phase 2 (kk = 1) ----
        {
            bf16x8 a1[4], b1[4];
            #pragma unroll
            for (int n = 0; n < 4; ++n)
                b1[n] = *(const bf16x8*)(&Bs[cur][(wn * 64 + n * 16 + l15) * 64 + ((4 + l4) ^ sx) * 8]);
            #pragma unroll
            for (int m = 0; m < 4; ++m)
                a1[m] = *(const bf16x8*)(&As[cur][(wm * 64 + m * 16 + l15) * 64 + ((4 + l4) ^ sx) * 8]);
            if (j < NTK - 2) stageB(sb, j + 2);
            __builtin_amdgcn_sched_barrier(0);
            __builtin_amdgcn_s_barrier();
            __builtin_amdgcn_sched_barrier(0);
            __builtin_amdgcn_s_setprio(1);
            #pragma unroll
            for (int m = 0; m < 4; ++m)
                #pragma unroll
                for (int n = 0; n < 4; ++n)
                    acc[m][n] = __builtin_amdgcn_mfma_f32_16x16x32_bf16(a1[m], b1[n], acc[m][n], 0, 0, 0);
            __builtin_amdgcn_s_setprio(0);
        }
        __builtin_amdgcn_sched_barrier(0);
        __builtin_amdgcn_s_barrier();

        cur = (cur == 2) ? 0 : cur + 1;
        sb  = (sb == 2) ? 0 : sb + 1;
    }

    if constexpr (MODE == 0) {
        int which = bx >> 3;     // 0=q 1=k 2=v (block is uniform)
        int b = by >> 3;
        #pragma unroll
        for (int n = 0; n < 4; ++n) {
            int col = bx * 128 + wn * 64 + n * 16 + l15;
            int c = col & 1023;
            int h = c >> 6, d = c & 63;
            size_t bh = (size_t)(b * HH + h);
            #pragma unroll
            for (int m = 0; m < 4; ++m) {
                int row = by * 256 + wm * 64 + m * 16 + l4 * 4;
                int t0 = row & 2047;
                if (which == 2) {
                    bf16x4 pk;
                    #pragma unroll
                    for (int i = 0; i < 4; ++i) pk[i] = (bf16)(acc[m][n][i] + bv[n]);
                    *(bf16x4*)((bf16*)out2 + (bh * DD + d) * TT + t0) = pk;
                } else {
                    bf16* dst = (bf16*)(which == 0 ? out0 : out1);
                    float sc = (which == 0) ? QSCALE : 1.f;
                    #pragma unroll
                    for (int i = 0; i < 4; ++i)
                        dst[(bh * TT + t0 + i) * DD + d] = (bf16)((acc[m][n][i] + bv[n]) * sc);
                }
            }
        }
    } else {
        #pragma unroll
        for (int m = 0; m < 4; ++m) {
            #pragma unroll
            for (int n = 0; n < 4; ++n) {
                int row = by * 256 + wm * 64 + m * 16 + l4 * 4;
                int col = bx * 128 + wn * 64 + n * 16 + l15;
                #pragma unroll
                for (int i = 0; i < 4; ++i)
                    ((float*)out0)[(size_t)(row + i) * N + col] = acc[m][n][i] + bv[n];
            }
        }
    }
}

// ---------------- causal flash attention (swapped-QK, dbuf, defer-max, in-reg P) ----------------
// Balanced pairing: grid y = 0..7; block processes q-tile (15-y) then (y):
// uniform 34 tiles per block, 512 equal blocks.
__global__ __launch_bounds__(256, 2) void attn_kernel(
    const bf16* __restrict__ Q, const bf16* __restrict__ Kb, const bf16* __restrict__ Vt,
    bf16* __restrict__ Y)
{
    constexpr int PD = 72;
    __shared__ bf16 Ks[2][64 * PD];   // [key][d]
    __shared__ bf16 Vs[2][64 * PD];   // [d][key]

    int bh = blockIdx.x;           // 0..63
    int b = bh >> 4, h = bh & 15;

    int tid = threadIdx.x;
    int lane = tid & 63, w = tid >> 6;
    int l15 = lane & 15, l4 = lane >> 4;

    const bf16* Qg = Q  + (size_t)bh * TT * DD;
    const bf16* Kg = Kb + (size_t)bh * TT * DD;
    const bf16* Vg = Vt + (size_t)bh * DD * TT;

    int sr = tid >> 3, sc = (tid & 7) * 8;

    #pragma unroll
    for (int part = 0; part < 2; ++part) {
        int qt = part == 0 ? (15 - (int)blockIdx.y) : (int)blockIdx.y;
        int q0 = qt * 128 + w * 32;    // wave's first q row

        bf16x8 qf[2][2];
        #pragma unroll
        for (int m = 0; m < 2; ++m)
            #pragma unroll
            for (int kk = 0; kk < 2; ++kk)
                qf[m][kk] = *(const bf16x8*)(Qg + (size_t)(q0 + m * 16 + l15) * DD + kk * 32 + l4 * 8);

        f32x4 o[2][4] = {};                 // o[mq][n]: q = q0+mq*16+l4*4+i, d = n*16+l15
        float mst[2] = {-1e30f, -1e30f};    // per q-row (ms, l15)
        float lst[2] = {0.f, 0.f};

        int NT = 2 * qt + 2;

        // incremental staging pointers
        const bf16* kp = Kg + (size_t)sr * DD + sc;
        const bf16* vp = Vg + (size_t)sr * TT + sc;
        bf16x8 kr0 = *(const bf16x8*)(kp);
        bf16x8 kr1 = *(const bf16x8*)(kp + 32 * DD);
        bf16x8 vr0 = *(const bf16x8*)(vp);
        bf16x8 vr1 = *(const bf16x8*)(vp + (size_t)32 * TT);
        kp += 64 * DD; vp += 64;

        for (int kt = 0; kt < NT; ++kt) {
            int buf = kt & 1;
            *(bf16x8*)(&Ks[buf][(size_t)sr * PD + sc])        = kr0;
            *(bf16x8*)(&Ks[buf][(size_t)(sr + 32) * PD + sc]) = kr1;
            *(bf16x8*)(&Vs[buf][(size_t)sr * PD + sc])        = vr0;
            *(bf16x8*)(&Vs[buf][(size_t)(sr + 32) * PD + sc]) = vr1;
            if (kt + 1 < NT) {
                kr0 = *(const bf16x8*)(kp);
                kr1 = *(const bf16x8*)(kp + 32 * DD);
                vr0 = *(const bf16x8*)(vp);
                vr1 = *(const bf16x8*)(vp + (size_t)32 * TT);
                kp += 64 * DD; vp += 64;
            }
            __syncthreads();

            if (kt * 64 <= q0 + 31) {
                int ktb = kt * 64;
                f32x4 s[2][4] = {};
                #pragma unroll
                for (int kk = 0; kk < 2; ++kk) {
                    bf16x8 kf[4];
                    #pragma unroll
                    for (int n = 0; n < 4; ++n)
                        kf[n] = *(const bf16x8*)(&Ks[buf][(n * 16 + l15) * PD + kk * 32 + l4 * 8]);
                    #pragma unroll
                    for (int ms = 0; ms < 2; ++ms)
                        #pragma unroll
                        for (int n = 0; n < 4; ++n)
                            s[ms][n] = __builtin_amdgcn_mfma_f32_16x16x32_bf16(kf[n], qf[ms][kk], s[ms][n], 0, 0, 0);
                }

                bf16x8 paf[2][2];
                #pragma unroll
                for (int ms = 0; ms < 2; ++ms) {
                    int qr = q0 + ms * 16 + l15;
                    if (ktb + 63 > q0 + ms * 16) {
                        #pragma unroll
                        for (int n = 0; n < 4; ++n) {
                            int keyb = ktb + n * 16 + l4 * 4;
                            #pragma unroll
                            for (int i = 0; i < 4; ++i)
                                if (keyb + i > qr) s[ms][n][i] = -1e30f;
                        }
                    }
                    float mx0 = fmaxf(fmaxf(s[ms][0][0], s[ms][0][1]), fmaxf(s[ms][0][2], s[ms][0][3]));
                    float mx1 = fmaxf(fmaxf(s[ms][1][0], s[ms][1][1]), fmaxf(s[ms][1][2], s[ms][1][3]));
                    float mx2 = fmaxf(fmaxf(s[ms][2][0], s[ms][2][1]), fmaxf(s[ms][2][2], s[ms][2][3]));
                    float mx3 = fmaxf(fmaxf(s[ms][3][0], s[ms][3][1]), fmaxf(s[ms][3][2], s[ms][3][3]));
                    float mx = fmaxf(fmaxf(mx0, mx1), fmaxf(mx2, mx3));
                    mx = fmaxf(mx, __shfl_xor(mx, 16));
                    mx = fmaxf(mx, __shfl_xor(mx, 32));

                    if (__any(mx > mst[ms] + 11.5f)) {
                        float mnew = fmaxf(mst[ms], mx);
                        float sc2 = ex2(mst[ms] - mnew);
                        mst[ms] = mnew;
                        lst[ms] *= sc2;
                        float scl[4];
                        #pragma unroll
                        for (int i = 0; i < 4; ++i) scl[i] = __shfl(sc2, l4 * 4 + i);
                        #pragma unroll
                        for (int n = 0; n < 4; ++n)
                            #pragma unroll
                            for (int i = 0; i < 4; ++i) o[ms][n][i] *= scl[i];
                    }

                    uint pk_[4][2];
                    float rs = 0.f;
                    #pragma unroll
                    for (int n = 0; n < 4; ++n) {
                        float p0 = ex2(s[ms][n][0] - mst[ms]);
                        float p1 = ex2(s[ms][n][1] - mst[ms]);
                        float p2 = ex2(s[ms][n][2] - mst[ms]);
                        float p3 = ex2(s[ms][n][3] - mst[ms]);
                        rs += (p0 + p1) + (p2 + p3);
                        asm("v_cvt_pk_bf16_f32 %0, %1, %2" : "=v"(pk_[n][0]) : "v"(p0), "v"(p1));
                        asm("v_cvt_pk_bf16_f32 %0, %1, %2" : "=v"(pk_[n][1]) : "v"(p2), "v"(p3));
                    }
                    rs += __shfl_xor(rs, 16);
                    rs += __shfl_xor(rs, 32);
                    lst[ms] += rs;

                    asm("v_permlane32_swap_b32 %0, %1" : "+v"(pk_[0][0]), "+v"(pk_[1][0]));
                    asm("v_permlane32_swap_b32 %0, %1" : "+v"(pk_[0][1]), "+v"(pk_[1][1]));
                    asm("v_permlane32_swap_b32 %0, %1" : "+v"(pk_[2][0]), "+v"(pk_[3][0]));
                    asm("v_permlane32_swap_b32 %0, %1" : "+v"(pk_[2][1]), "+v"(pk_[3][1]));
                    asm("v_permlane16_swap_b32 %0, %1" : "+v"(pk_[0][0]), "+v"(pk_[1][0]));
                    asm("v_permlane16_swap_b32 %0, %1" : "+v"(pk_[0][1]), "+v"(pk_[1][1]));
                    asm("v_permlane16_swap_b32 %0, %1" : "+v"(pk_[2][0]), "+v"(pk_[3][0]));
                    asm("v_permlane16_swap_b32 %0, %1" : "+v"(pk_[2][1]), "+v"(pk_[3][1]));
                    uint4 u0 = {pk_[0][0], pk_[0][1], pk_[1][0], pk_[1][1]};
                    uint4 u1 = {pk_[2][0], pk_[2][1], pk_[3][0], pk_[3][1]};
                    paf[ms][0] = __builtin_bit_cast(bf16x8, u0);
                    paf[ms][1] = __builtin_bit_cast(bf16x8, u1);
                }

                #pragma unroll
                for (int kk = 0; kk < 2; ++kk) {
                    bf16x8 vf[4];
                    #pragma unroll
                    for (int n = 0; n < 4; ++n)
                        vf[n] = *(const bf16x8*)(&Vs[buf][(n * 16 + l15) * PD + kk * 32 + l4 * 8]);
                    #pragma unroll
                    for (int mq = 0; mq < 2; ++mq)
                        #pragma unroll
                        for (int n = 0; n < 4; ++n)
                            o[mq][n] = __builtin_amdgcn_mfma_f32_16x16x32_bf16(paf[mq][kk], vf[n], o[mq][n], 0, 0, 0);
                }
            }
        }

        #pragma unroll
        for (int mq = 0; mq < 2; ++mq) {
            float inv[4];
            #pragma unroll
            for (int i = 0; i < 4; ++i) inv[i] = 1.f / __shfl(lst[mq], l4 * 4 + i);
            #pragma unroll
            for (int i = 0; i < 4; ++i) {
                int t = q0 + mq * 16 + l4 * 4 + i;
                #pragma unroll
                for (int n = 0; n < 4; ++n) {
                    int d = n * 16 + l15;
                    Y[((size_t)(b * TT + t)) * CC + h * DD + d] = (bf16)(o[mq][n][i] * inv[i]);
                }
            }
        }
    }
}

extern "C" void kernel_launch(void* const* d_in, const int* in_sizes, int n_in,
                              void* d_out, int out_size, void* d_ws, size_t ws_size,
                              hipStream_t stream) {
    const float* x      = (const float*)d_in[0];
    const float* w_attn = (const float*)d_in[1];
    const float* b_attn = (const float*)d_in[2];
    const float* w_proj = (const float*)d_in[3];
    const float* b_proj = (const float*)d_in[4];
    float* out = (float*)d_out;

    bf16* xb  = (bf16*)d_ws;                        // [8192][1024]
    bf16* waT = xb  + (size_t)MM * CC;              // [3072][1024]
    bf16* wpT = waT + (size_t)3 * CC * CC;          // [1024][1024]
    bf16* qb  = wpT + (size_t)CC * CC;              // [B*H][T][D]
    bf16* kb  = qb  + (size_t)MM * CC;              // [B*H][T][D]
    bf16* vt  = kb  + (size_t)MM * CC;              // [B*H][D][T] (written directly by gemm8<0>)
    bf16* yb  = vt  + (size_t)MM * CC;              // [8192][1024] attention output

    conv_f32_bf16<<<2048, 256, 0, stream>>>(x, xb, MM * CC);
    transpose_f32_bf16<<<dim3(3 * CC / 64, CC / 64), 256, 0, stream>>>(w_attn, waT, CC, 3 * CC);
    transpose_f32_bf16<<<dim3(CC / 64, CC / 64), 256, 0, stream>>>(w_proj, wpT, CC, CC);

    gemm8<0><<<dim3(3 * CC / 128, MM / 256), 512, 0, stream>>>(
        xb, waT, b_attn, qb, kb, vt, MM, 3 * CC, CC);

    attn_kernel<<<dim3(BB * HH, 8), 256, 0, stream>>>(qb, kb, vt, yb);

    gemm8<1><<<dim3(CC / 128, MM / 256), 512, 0, stream>>>(
        yb, wpT, b_proj, out, nullptr, nullptr, MM, CC, CC);
}